// Round 13
// baseline (179.152 us; speedup 1.0000x reference)
//
#include <hip/hip_runtime.h>
#include <stdint.h>

// HMM trajectory-net forward:  -logsumexp over an 8191-step 64-state HMM scan.
// Pipeline:
//   conv_*       : fp32 -> bf16 repacks
//   small_gemm   : start/stop logits via MFMA, fused softmax/sigmoid -> ps, pb, pc
//   act_gemm     : B-group in LDS staged ONCE per 8 t-subtiles; 2 m-frags/wave so
//                  each ds_read feeds 2 MFMAs; fused no-max softmax -> peT[b][t]
//   chunk_kernel : 128 chunks x 64 steps; 4 waves/chunk, 64x64 transfer matrix in
//                  registers; scalars staged in LDS (2-pass for peT layout)
//   group_combine: 16 blocks x 7 matmuls, LDS-resident operands, double-buffered
//                  global->LDS prefetch of the next matrix (latency hidden)
//   final_combine: 16 sequential mat-vecs (4-wave split) + boundary terms -> scalar

typedef short bf16x8 __attribute__((ext_vector_type(8)));
typedef float f32x4  __attribute__((ext_vector_type(4)));
typedef unsigned short u16;

#define T_LEN 8192
#define SDIM  256

// ---- workspace layout (bytes) ----
#define WS_SBF    0              // 8256*256 bf16 (padded rows zeroed)
#define WS_WAT    4227072        // 4096*256 bf16  [b*64+n][s]
#define WS_WSMT   6324224        // 192*256 bf16   [col][s]
#define WS_PE     6422528        // peT: 64*8192 f32  [b][t]
#define WS_PS     8519680        // 8193*64 f32
#define WS_PB     10617088       // 8193*64 f32
#define WS_PC     12714496       // 8193*64 f32   (dead after chunk_kernel -> reused for Gout)
#define WS_MOUT   14811904       // 128*4096 f32  [chunk][k][j]
#define WS_LSC    16909056       // 128 f32
#define WS_GOUT   WS_PC                      // 16*4096 f32 (reuses pc region)
#define WS_GLSC   (WS_PC + 262144)           // 16 f32

__device__ inline u16 f2bf(float f) {
  union { float f; uint32_t u; } v; v.f = f;
  uint32_t u = v.u;
  return (u16)((u + 0x7fffu + ((u >> 16) & 1u)) >> 16);
}

// ---------------- converts ----------------
__global__ void conv_s(const float* __restrict__ s_i, u16* __restrict__ s_bf) {
  int idx = blockIdx.x * 256 + threadIdx.x;
  int t = idx >> 8;
  float v = (t < T_LEN + 1) ? s_i[idx] : 0.f;
  s_bf[idx] = f2bf(v);
}

__global__ void conv_wa(const float* __restrict__ Wa, u16* __restrict__ wa_t) {
  int idx = blockIdx.x * 256 + threadIdx.x;
  int s = idx >> 12, bn = idx & 4095;
  wa_t[bn * 256 + s] = f2bf(Wa[idx]);
}

__global__ void conv_wsm(const float* __restrict__ Wstop, const float* __restrict__ Wstart,
                         u16* __restrict__ wsm_t) {
  int idx = blockIdx.x * 256 + threadIdx.x;
  int col = idx >> 8, s = idx & 255;
  float v;
  if (col < 64)       v = Wstart[s * 64 + col];
  else if (col < 128) v = Wstop[s * 128 + (col - 64) * 2 + 0];
  else                v = Wstop[s * 128 + (col - 128) * 2 + 1];
  wsm_t[col * 256 + s] = f2bf(v);
}

// ---------------- action GEMM + fused emit ----------------
// Grid: 512 blocks = 8 t-slabs x 64 b-groups; slab = bid & 7 -> one slab per XCD.
// Block: 256 threads = 4 waves; wave owns 32 t-rows (2 m-frags) per iter, 8 iters.
// B-group (64x256 bf16, 32 KB) staged to LDS ONCE (amortized over 8 subtiles,
// single barrier).  Each ds_read_b128 of a B-frag feeds TWO MFMAs (halves LDS
// traffic vs 1 m-frag/wave).  A loaded direct global->VGPR, next-iter prefetch.
// Epilogue: no-max softmax (logits ~N(0,0.32^2)), pe = exp(v_sel)/sum(exp),
// transposed store peT[b][t].
__global__ __launch_bounds__(256, 2) void act_gemm(
    const u16* __restrict__ s_bf, const u16* __restrict__ wa_t,
    const int* __restrict__ actions, float* __restrict__ peT) {
  __shared__ uint4 ldsB[64 * 32];
  const int tid = threadIdx.x;
  const int lane = tid & 63;
  const int wmv = tid >> 6;            // 0..3
  const int g = lane >> 4, c = lane & 15;

  const int bid = blockIdx.x;
  const int slab = bid & 7;            // t-slab (XCD-local)
  const int b0 = bid >> 3;             // b-group

  // stage B-group (64 rows x 256 k) into LDS, XOR-swizzled slots
  {
    const u16* bsrc = wa_t + (size_t)b0 * 64 * 256;
#pragma unroll
    for (int it = 0; it < 8; ++it) {
      int i = tid + 256 * it;
      int r = i >> 5, s = i & 31;
      ldsB[r * 32 + (s ^ (r & 7))] = *(const uint4*)(bsrc + r * 256 + s * 8);
    }
  }

  const size_t pebase = (size_t)b0 * 8192;
  const int tw = slab * 1024 + wmv * 32;

  // prefetch A for iter 0 (2 m-frags x 8 ks)
  bf16x8 af[2][8], afn[2][8];
  {
    const u16* ar0 = s_bf + (size_t)(tw + c) * 256 + g * 8;
    const u16* ar1 = s_bf + (size_t)(tw + 16 + c) * 256 + g * 8;
#pragma unroll
    for (int ks = 0; ks < 8; ++ks) {
      af[0][ks] = *(const bf16x8*)(ar0 + ks * 32);
      af[1][ks] = *(const bf16x8*)(ar1 + ks * 32);
    }
  }
  __syncthreads();   // B staged (A-prefetch overlapped with staging)

#pragma unroll 1
  for (int it = 0; it < 8; ++it) {
    const int tbase = tw + it * 128;

    // prefetch next iter's A (latency hides under MFMA + epilogue)
    if (it < 7) {
      const u16* ar0 = s_bf + (size_t)(tbase + 128 + c) * 256 + g * 8;
      const u16* ar1 = s_bf + (size_t)(tbase + 144 + c) * 256 + g * 8;
#pragma unroll
      for (int ks = 0; ks < 8; ++ks) {
        afn[0][ks] = *(const bf16x8*)(ar0 + ks * 32);
        afn[1][ks] = *(const bf16x8*)(ar1 + ks * 32);
      }
    }

    f32x4 acc[2][4];
#pragma unroll
    for (int mf = 0; mf < 2; ++mf)
#pragma unroll
      for (int nf = 0; nf < 4; ++nf) acc[mf][nf] = (f32x4){0.f, 0.f, 0.f, 0.f};

#pragma unroll
    for (int ks = 0; ks < 8; ++ks) {
#pragma unroll
      for (int nf = 0; nf < 4; ++nf) {
        int rr = nf * 16 + c;
        bf16x8 bfv = *(const bf16x8*)&ldsB[rr * 32 + ((ks * 4 + g) ^ (rr & 7))];
        acc[0][nf] = __builtin_amdgcn_mfma_f32_16x16x32_bf16(af[0][ks], bfv, acc[0][nf], 0, 0, 0);
        acc[1][nf] = __builtin_amdgcn_mfma_f32_16x16x32_bf16(af[1][ks], bfv, acc[1][nf], 0, 0, 0);
      }
    }

    // epilogue: per m-frag, row g*4+q; no-max softmax over 64 cols
#pragma unroll
    for (int mf = 0; mf < 2; ++mf) {
#pragma unroll
      for (int q = 0; q < 4; ++q) {
        float e0 = __expf(acc[mf][0][q]);
        float e1 = __expf(acc[mf][1][q]);
        float e2 = __expf(acc[mf][2][q]);
        float e3 = __expf(acc[mf][3][q]);
        float s = (e0 + e1) + (e2 + e3);
#pragma unroll
        for (int d = 1; d < 16; d <<= 1) s += __shfl_xor(s, d);
        int a = actions[tbase + mf * 16 + g * 4 + q];
        int acf = a >> 4;
        float esel = (acf == 0) ? e0 : (acf == 1) ? e1 : (acf == 2) ? e2 : e3;
        if (c == (a & 15))
          peT[pebase + tbase + mf * 16 + g * 4 + q] = esel / s;
      }
    }

#pragma unroll
    for (int ks = 0; ks < 8; ++ks) {
      af[0][ks] = afn[0][ks];
      af[1][ks] = afn[1][ks];
    }
  }
}

// ---------------- start/stop GEMM + fused softmax/sigmoid ----------------
__global__ __launch_bounds__(256) void small_gemm(
    const u16* __restrict__ s_bf, const u16* __restrict__ wsm_t,
    float* __restrict__ ps, float* __restrict__ pb, float* __restrict__ pc) {
  __shared__ uint4 ldsA[64 * 16];
  __shared__ uint4 ldsB[192 * 16];
  const int t0 = blockIdx.x * 64;
  const int tid = threadIdx.x;
  const int lane = tid & 63, w = tid >> 6;
  const int g = lane >> 4, c = lane & 15;

  f32x4 acc[12];
#pragma unroll
  for (int i = 0; i < 12; ++i) acc[i] = (f32x4){0.f, 0.f, 0.f, 0.f};

  for (int kh = 0; kh < 2; ++kh) {
    if (kh) __syncthreads();
    for (int i = tid; i < 64 * 16; i += 256) {
      int row = i >> 4, u = i & 15;
      ldsA[(row * 16 + u) ^ (row & 7)] =
          *(const uint4*)(s_bf + (size_t)(t0 + row) * 256 + kh * 128 + u * 8);
    }
    for (int i = tid; i < 192 * 16; i += 256) {
      int row = i >> 4, u = i & 15;
      ldsB[(row * 16 + u) ^ (row & 7)] =
          *(const uint4*)(wsm_t + (size_t)row * 256 + kh * 128 + u * 8);
    }
    __syncthreads();
#pragma unroll
    for (int kk = 0; kk < 4; ++kk) {
      int u = kk * 4 + g;
      int arow = w * 16 + c;
      bf16x8 af = *(const bf16x8*)&ldsA[(arow * 16 + u) ^ (arow & 7)];
#pragma unroll
      for (int cf = 0; cf < 12; ++cf) {
        int brow = cf * 16 + c;
        bf16x8 bfr = *(const bf16x8*)&ldsB[(brow * 16 + u) ^ (brow & 7)];
        acc[cf] = __builtin_amdgcn_mfma_f32_16x16x32_bf16(af, bfr, acc[cf], 0, 0, 0);
      }
    }
  }

#pragma unroll
  for (int q = 0; q < 4; ++q) {
    int t = t0 + w * 16 + g * 4 + q;
    float v0 = acc[0][q], v1 = acc[1][q], v2 = acc[2][q], v3 = acc[3][q];
    float m = fmaxf(fmaxf(v0, v1), fmaxf(v2, v3));
#pragma unroll
    for (int d = 1; d < 16; d <<= 1) m = fmaxf(m, __shfl_xor(m, d));
    float s = __expf(v0 - m) + __expf(v1 - m) + __expf(v2 - m) + __expf(v3 - m);
#pragma unroll
    for (int d = 1; d < 16; d <<= 1) s += __shfl_xor(s, d);
    float lse = m + __logf(s);
    if (t <= T_LEN) {
      ps[t * 64 + 0 * 16 + c] = __expf(v0 - lse);
      ps[t * 64 + 1 * 16 + c] = __expf(v1 - lse);
      ps[t * 64 + 2 * 16 + c] = __expf(v2 - lse);
      ps[t * 64 + 3 * 16 + c] = __expf(v3 - lse);
#pragma unroll
      for (int bf = 0; bf < 4; ++bf) {
        float l0 = acc[4 + bf][q], l1 = acc[8 + bf][q];
        float d01 = l0 - l1;
        pb[t * 64 + bf * 16 + c] = 1.f / (1.f + __expf(-d01));
        pc[t * 64 + bf * 16 + c] = 1.f / (1.f + __expf(d01));
      }
    }
  }
}

// ---------------- chunked scan: 4 waves per chunk ----------------
__global__ __launch_bounds__(256) void chunk_kernel(
    const float* __restrict__ peT, const float* __restrict__ ps,
    const float* __restrict__ pb, const float* __restrict__ pc,
    float* __restrict__ Mout, float* __restrict__ lscale) {
  __shared__ float scal[64 * 196];   // per step: [b(64) | ec(64) | es(64) | pad]
  __shared__ float part[2][256];
  __shared__ float mxs[4];
  const int ck = blockIdx.x;
  const int tid = threadIdx.x;
  const int lane = tid & 63;
  const int w = tid >> 6;
  const int tlo = ck * 64 + 1;

#pragma unroll
  for (int it = 0; it < 16; ++it) {
    int i = tid + 256 * it;
    int st = i >> 6, j = i & 63;
    int t = tlo + st;
    if (t <= T_LEN - 1) {
      int base = t * 64 + j;
      scal[st * 196 + j]       = pb[base];
      scal[st * 196 + 64 + j]  = pc[base];
      scal[st * 196 + 128 + j] = ps[base];
    } else {
      scal[st * 196 + j]       = 0.f;
      scal[st * 196 + 64 + j]  = 1.f;
      scal[st * 196 + 128 + j] = 0.f;
    }
  }
  __syncthreads();
#pragma unroll
  for (int it = 0; it < 16; ++it) {
    int i = tid + 256 * it;
    int j = i >> 6, st = i & 63;
    int t = tlo + st;
    if (t <= T_LEN - 1) {
      float e = peT[(size_t)j * 8192 + t];
      scal[st * 196 + 64 + j]  *= e;
      scal[st * 196 + 128 + j] *= e;
    }
  }
  __syncthreads();

  float M[16];
#pragma unroll
  for (int jj = 0; jj < 16; ++jj) M[jj] = ((w * 16 + jj) == lane) ? 1.f : 0.f;
  float lsc = 0.f;
  int pbuf = 0;

  for (int st = 0; st < 64; ++st) {
    const float* sb = &scal[st * 196];
    float p0 = 0.f, p1 = 0.f, p2 = 0.f, p3 = 0.f;
#pragma unroll
    for (int q = 0; q < 4; ++q) {
      float4 bq = *(const float4*)(sb + w * 16 + q * 4);
      p0 = fmaf(bq.x, M[q * 4 + 0], p0);
      p1 = fmaf(bq.y, M[q * 4 + 1], p1);
      p2 = fmaf(bq.z, M[q * 4 + 2], p2);
      p3 = fmaf(bq.w, M[q * 4 + 3], p3);
    }
    part[pbuf][w * 64 + lane] = (p0 + p1) + (p2 + p3);
    __syncthreads();
    float wv = part[pbuf][lane] + part[pbuf][64 + lane] +
               part[pbuf][128 + lane] + part[pbuf][192 + lane];
    pbuf ^= 1;
#pragma unroll
    for (int q = 0; q < 4; ++q) {
      float4 ecq = *(const float4*)(sb + 64 + w * 16 + q * 4);
      float4 esq = *(const float4*)(sb + 128 + w * 16 + q * 4);
      M[q * 4 + 0] = fmaf(ecq.x, M[q * 4 + 0], esq.x * wv);
      M[q * 4 + 1] = fmaf(ecq.y, M[q * 4 + 1], esq.y * wv);
      M[q * 4 + 2] = fmaf(ecq.z, M[q * 4 + 2], esq.z * wv);
      M[q * 4 + 3] = fmaf(ecq.w, M[q * 4 + 3], esq.w * wv);
    }
    if ((st & 7) == 7) {
      float mx = M[0];
#pragma unroll
      for (int jj = 1; jj < 16; ++jj) mx = fmaxf(mx, M[jj]);
#pragma unroll
      for (int d = 1; d < 64; d <<= 1) mx = fmaxf(mx, __shfl_xor(mx, d));
      if (lane == 0) mxs[w] = mx;
      __syncthreads();
      float bm = fmaxf(fmaxf(mxs[0], mxs[1]), fmaxf(mxs[2], mxs[3]));
      float inv = 1.f / bm;
#pragma unroll
      for (int jj = 0; jj < 16; ++jj) M[jj] *= inv;
      lsc += __logf(bm);
    }
  }

  float* out = Mout + (size_t)ck * 4096;
#pragma unroll
  for (int q = 0; q < 4; ++q) {
    float4 v = make_float4(M[q * 4 + 0], M[q * 4 + 1], M[q * 4 + 2], M[q * 4 + 3]);
    *(float4*)(out + lane * 64 + w * 16 + q * 4) = v;
  }
  if (tid == 0) lscale[ck] = lsc;
}

// ---------------- level-1 combine: 16 groups x 8 chunk matrices ----------------
__global__ __launch_bounds__(256) void group_combine(
    const float* __restrict__ Mout, const float* __restrict__ lscale,
    float* __restrict__ Gout, float* __restrict__ glsc) {
  const int g = blockIdx.x;
  const int tid = threadIdx.x;
  const int j = tid & 63;
  const int w = tid >> 6;
  __shared__ float Xa[64 * 68];
  __shared__ float Xb[64 * 68];
  __shared__ float Ma[64 * 68];
  __shared__ float Mb[64 * 68];
  __shared__ float red[4];

  {
    const float* M0 = Mout + (size_t)(8 * g) * 4096;
    const float* M1 = Mout + (size_t)(8 * g + 1) * 4096;
    for (int idx = tid; idx < 4096; idx += 256) {
      int i = idx >> 6, r = idx & 63;
      Xa[r * 68 + i] = M0[idx];
      Ma[i * 68 + r] = M1[idx];
    }
  }
  __syncthreads();

  float lsc = 0.f;
  float* Xcur = Xa; float* Xnxt = Xb;
  float* Mcur = Ma; float* Mnxt = Mb;

  for (int m = 1; m < 8; ++m) {
    float4 pf[4];
    if (m < 7) {
      const float* Mn = Mout + (size_t)(8 * g + m + 1) * 4096;
#pragma unroll
      for (int ii = 0; ii < 4; ++ii)
        pf[ii] = *(const float4*)(Mn + tid * 4 + 1024 * ii);
    }

    float acc[16];
#pragma unroll
    for (int i = 0; i < 16; ++i) acc[i] = 0.f;

#pragma unroll 4
    for (int k = 0; k < 64; ++k) {
      float mv = Mcur[k * 68 + j];
      const float* xr = Xcur + k * 68 + (w << 4);
      float4 x0 = *(const float4*)(xr + 0);
      float4 x1 = *(const float4*)(xr + 4);
      float4 x2 = *(const float4*)(xr + 8);
      float4 x3 = *(const float4*)(xr + 12);
      acc[0]  = fmaf(mv, x0.x, acc[0]);  acc[1]  = fmaf(mv, x0.y, acc[1]);
      acc[2]  = fmaf(mv, x0.z, acc[2]);  acc[3]  = fmaf(mv, x0.w, acc[3]);
      acc[4]  = fmaf(mv, x1.x, acc[4]);  acc[5]  = fmaf(mv, x1.y, acc[5]);
      acc[6]  = fmaf(mv, x1.z, acc[6]);  acc[7]  = fmaf(mv, x1.w, acc[7]);
      acc[8]  = fmaf(mv, x2.x, acc[8]);  acc[9]  = fmaf(mv, x2.y, acc[9]);
      acc[10] = fmaf(mv, x2.z, acc[10]); acc[11] = fmaf(mv, x2.w, acc[11]);
      acc[12] = fmaf(mv, x3.x, acc[12]); acc[13] = fmaf(mv, x3.y, acc[13]);
      acc[14] = fmaf(mv, x3.z, acc[14]); acc[15] = fmaf(mv, x3.w, acc[15]);
    }

    float lm = acc[0];
#pragma unroll
    for (int i = 1; i < 16; ++i) lm = fmaxf(lm, acc[i]);
#pragma unroll
    for (int d = 1; d < 64; d <<= 1) lm = fmaxf(lm, __shfl_xor(lm, d));
    if ((tid & 63) == 0) red[w] = lm;
    __syncthreads();
    float bm = fmaxf(fmaxf(red[0], red[1]), fmaxf(red[2], red[3]));
    float inv = 1.f / bm;
    lsc += __logf(bm);
#pragma unroll
    for (int i = 0; i < 16; ++i)
      Xnxt[j * 68 + (w << 4) + i] = acc[i] * inv;
    if (m < 7) {
#pragma unroll
      for (int ii = 0; ii < 4; ++ii) {
        int idx = tid * 4 + 1024 * ii;
        int k = idx >> 6, jj = idx & 63;
        *(float4*)(Mnxt + k * 68 + jj) = pf[ii];
      }
    }
    __syncthreads();
    float* t = Xcur; Xcur = Xnxt; Xnxt = t;
    float* tm = Mcur; Mcur = Mnxt; Mnxt = tm;
  }

  float* out = Gout + (size_t)g * 4096;
  for (int idx = tid; idx < 4096; idx += 256) {
    int i = idx >> 6, r = idx & 63;
    out[idx] = Xcur[r * 68 + i];
  }
  if (tid == 0) {
    float s = lsc;
#pragma unroll
    for (int m = 0; m < 8; ++m) s += lscale[8 * g + m];
    glsc[g] = s;
  }
}

// ---------------- level-2 combine: 16 sequential mat-vecs ----------------
__global__ __launch_bounds__(256) void final_combine(
    const float* __restrict__ Gout, const float* __restrict__ glsc,
    const float* __restrict__ peT, const float* __restrict__ ps,
    const float* __restrict__ pb, float* __restrict__ out) {
  const int tid = threadIdx.x;
  const int j = tid & 63, w = tid >> 6;
  __shared__ float vsh[64];
  __shared__ float part[4 * 64];
  if (tid < 64) vsh[tid] = ps[tid] * peT[(size_t)tid * 8192];   // f0
  __syncthreads();
  double lsc = 0.0;
  for (int gph = 0; gph < 16; ++gph) {
    const float* Gc = Gout + (size_t)gph * 4096;
    const int k0 = w << 4;
    float a0 = 0.f, a1 = 0.f, a2 = 0.f, a3 = 0.f;
#pragma unroll
    for (int kk = 0; kk < 16; kk += 4) {
      a0 = fmaf(vsh[k0 + kk + 0], Gc[(k0 + kk + 0) * 64 + j], a0);
      a1 = fmaf(vsh[k0 + kk + 1], Gc[(k0 + kk + 1) * 64 + j], a1);
      a2 = fmaf(vsh[k0 + kk + 2], Gc[(k0 + kk + 2) * 64 + j], a2);
      a3 = fmaf(vsh[k0 + kk + 3], Gc[(k0 + kk + 3) * 64 + j], a3);
    }
    part[w * 64 + j] = (a0 + a1) + (a2 + a3);
    __syncthreads();
    if (w == 0) {
      float u = part[j] + part[64 + j] + part[128 + j] + part[192 + j];
      float mx = u;
#pragma unroll
      for (int d = 1; d < 64; d <<= 1) mx = fmaxf(mx, __shfl_xor(mx, d));
      vsh[j] = u / mx;
      lsc += (double)__logf(mx) + (double)glsc[gph];
    }
    __syncthreads();
  }
  if (w == 0) {
    float z = vsh[j] * pb[T_LEN * 64 + j];
#pragma unroll
    for (int d = 1; d < 64; d <<= 1) z += __shfl_xor(z, d);
    if (j == 0) out[0] = (float)(-((double)logf(z) + lsc));
  }
}

extern "C" void kernel_launch(void* const* d_in, const int* in_sizes, int n_in,
                              void* d_out, int out_size, void* d_ws, size_t ws_size,
                              hipStream_t stream) {
  const float* s_i      = (const float*)d_in[0];
  const float* W_action = (const float*)d_in[1];
  const float* W_stop   = (const float*)d_in[2];
  const float* W_start  = (const float*)d_in[3];
  const int*   actions  = (const int*)d_in[4];

  char* ws = (char*)d_ws;
  u16*   s_bf  = (u16*)(ws + WS_SBF);
  u16*   wa_t  = (u16*)(ws + WS_WAT);
  u16*   wsm_t = (u16*)(ws + WS_WSMT);
  float* peT   = (float*)(ws + WS_PE);
  float* ps    = (float*)(ws + WS_PS);
  float* pb    = (float*)(ws + WS_PB);
  float* pc    = (float*)(ws + WS_PC);
  float* Mout  = (float*)(ws + WS_MOUT);
  float* lsc   = (float*)(ws + WS_LSC);
  float* Gout  = (float*)(ws + WS_GOUT);
  float* glsc  = (float*)(ws + WS_GLSC);

  conv_s<<<8256, 256, 0, stream>>>(s_i, s_bf);
  conv_wa<<<4096, 256, 0, stream>>>(W_action, wa_t);
  conv_wsm<<<192, 256, 0, stream>>>(W_stop, W_start, wsm_t);
  small_gemm<<<129, 256, 0, stream>>>(s_bf, wsm_t, ps, pb, pc);
  act_gemm<<<512, 256, 0, stream>>>(s_bf, wa_t, actions, peT);
  chunk_kernel<<<128, 256, 0, stream>>>(peT, ps, pb, pc, Mout, lsc);
  group_combine<<<16, 256, 0, stream>>>(Mout, lsc, Gout, glsc);
  final_combine<<<1, 256, 0, stream>>>(Gout, glsc, peT, ps, pb, (float*)d_out);
}

// Round 14
// 135.862 us; speedup vs baseline: 1.3186x; 1.3186x over previous
//
#include <hip/hip_runtime.h>
#include <stdint.h>

// HMM trajectory-net forward:  -logsumexp over an 8191-step 64-state HMM scan.
// Pipeline (5 launches):
//   conv_all     : fused fp32 -> bf16 repacks (s_i, W_action, W_stop/start)
//   gemm_fused   : blocks 0..128 = start/stop GEMM (ps,pb,pc);
//                  blocks 129..4224 = action GEMM (R10 structure: B-group in LDS,
//                  A direct L2->VGPR, no mid-loop barriers, no-max softmax -> peT)
//   chunk_kernel : 128 chunks x 64 steps; 4 waves/chunk, transfer matrix in regs
//   group_combine: 16 blocks x 7 matmuls, LDS-resident, double-buffered prefetch
//   final_combine: 16 sequential mat-vecs + boundary terms -> scalar

typedef short bf16x8 __attribute__((ext_vector_type(8)));
typedef float f32x4  __attribute__((ext_vector_type(4)));
typedef unsigned short u16;

#define T_LEN 8192
#define SDIM  256

// ---- workspace layout (bytes) ----
#define WS_SBF    0              // 8256*256 bf16 (padded rows zeroed)
#define WS_WAT    4227072        // 4096*256 bf16  [b*64+n][s]
#define WS_WSMT   6324224        // 192*256 bf16   [col][s]
#define WS_PE     6422528        // peT: 64*8192 f32  [b][t]
#define WS_PS     8519680        // 8193*64 f32
#define WS_PB     10617088       // 8193*64 f32
#define WS_PC     12714496       // 8193*64 f32   (dead after chunk_kernel -> reused for Gout)
#define WS_MOUT   14811904       // 128*4096 f32  [chunk][k][j]
#define WS_LSC    16909056       // 128 f32
#define WS_GOUT   WS_PC                      // 16*4096 f32 (reuses pc region)
#define WS_GLSC   (WS_PC + 262144)           // 16 f32

__device__ inline u16 f2bf(float f) {
  union { float f; uint32_t u; } v; v.f = f;
  uint32_t u = v.u;
  return (u16)((u + 0x7fffu + ((u >> 16) & 1u)) >> 16);
}

// ---------------- fused converts ----------------
__global__ void conv_all(const float* __restrict__ s_i, const float* __restrict__ Wa,
                         const float* __restrict__ Wstop, const float* __restrict__ Wstart,
                         u16* __restrict__ s_bf, u16* __restrict__ wa_t,
                         u16* __restrict__ wsm_t) {
  const int bid = blockIdx.x;
  const int tid = threadIdx.x;
  if (bid < 8256) {                       // s_i -> s_bf (padded)
    int idx = bid * 256 + tid;
    int t = idx >> 8;
    float v = (t < T_LEN + 1) ? s_i[idx] : 0.f;
    s_bf[idx] = f2bf(v);
  } else if (bid < 8256 + 4096) {         // W_action -> wa_t (transposed)
    int idx = (bid - 8256) * 256 + tid;
    int s = idx >> 12, bn = idx & 4095;
    wa_t[bn * 256 + s] = f2bf(Wa[idx]);
  } else {                                // W_stop/W_start -> wsm_t
    int idx = (bid - 12352) * 256 + tid;
    int col = idx >> 8, s = idx & 255;
    float v;
    if (col < 64)       v = Wstart[s * 64 + col];
    else if (col < 128) v = Wstop[s * 128 + (col - 64) * 2 + 0];
    else                v = Wstop[s * 128 + (col - 128) * 2 + 1];
    wsm_t[col * 256 + s] = f2bf(v);
  }
}

// ---------------- fused GEMMs ----------------
// bid < 129 : start/stop GEMM (64 t-rows, K staged in 4 quarters, 32KB LDS)
// bid >= 129: action GEMM, R10 structure: tile 128t x 64n, B-group staged once
//             (32KB, XOR-swizzled), A direct global->VGPR in two batches, ONE
//             barrier, no-max softmax epilogue, transposed store peT[b][t].
__global__ __launch_bounds__(256, 4) void gemm_fused(
    const u16* __restrict__ s_bf, const u16* __restrict__ wa_t,
    const u16* __restrict__ wsm_t, const int* __restrict__ actions,
    float* __restrict__ peT, float* __restrict__ ps,
    float* __restrict__ pb, float* __restrict__ pc) {
  __shared__ uint4 ldsU[64 * 32];   // 32KB, shared by both paths
  const int tid = threadIdx.x;
  const int lane = tid & 63;
  const int w = tid >> 6;
  const int g = lane >> 4, c = lane & 15;
  const int bid = blockIdx.x;

  if (bid < 129) {
    // ---------- small path: start/stop logits + softmax/sigmoid ----------
    uint4* sA = ldsU;          // 64 rows x 8 slots
    uint4* sB = ldsU + 512;    // 192 rows x 8 slots
    const int t0 = bid * 64;

    f32x4 acc[12];
#pragma unroll
    for (int i = 0; i < 12; ++i) acc[i] = (f32x4){0.f, 0.f, 0.f, 0.f};

    for (int kq = 0; kq < 4; ++kq) {
      if (kq) __syncthreads();
#pragma unroll
      for (int i = tid; i < 512; i += 256) {
        int row = i >> 3, u = i & 7;
        sA[row * 8 + (u ^ (row & 7))] =
            *(const uint4*)(s_bf + (size_t)(t0 + row) * 256 + kq * 64 + u * 8);
      }
#pragma unroll
      for (int i = tid; i < 1536; i += 256) {
        int row = i >> 3, u = i & 7;
        sB[row * 8 + (u ^ (row & 7))] =
            *(const uint4*)(wsm_t + (size_t)row * 256 + kq * 64 + u * 8);
      }
      __syncthreads();
#pragma unroll
      for (int kk = 0; kk < 2; ++kk) {
        int u = kk * 4 + g;
        int arow = w * 16 + c;
        bf16x8 af = *(const bf16x8*)&sA[arow * 8 + (u ^ (arow & 7))];
#pragma unroll
        for (int cf = 0; cf < 12; ++cf) {
          int brow = cf * 16 + c;
          bf16x8 bfr = *(const bf16x8*)&sB[brow * 8 + (u ^ (brow & 7))];
          acc[cf] = __builtin_amdgcn_mfma_f32_16x16x32_bf16(af, bfr, acc[cf], 0, 0, 0);
        }
      }
    }

#pragma unroll
    for (int q = 0; q < 4; ++q) {
      int t = t0 + w * 16 + g * 4 + q;
      float v0 = acc[0][q], v1 = acc[1][q], v2 = acc[2][q], v3 = acc[3][q];
      float m = fmaxf(fmaxf(v0, v1), fmaxf(v2, v3));
#pragma unroll
      for (int d = 1; d < 16; d <<= 1) m = fmaxf(m, __shfl_xor(m, d));
      float s = __expf(v0 - m) + __expf(v1 - m) + __expf(v2 - m) + __expf(v3 - m);
#pragma unroll
      for (int d = 1; d < 16; d <<= 1) s += __shfl_xor(s, d);
      float lse = m + __logf(s);
      if (t <= T_LEN) {
        ps[t * 64 + 0 * 16 + c] = __expf(v0 - lse);
        ps[t * 64 + 1 * 16 + c] = __expf(v1 - lse);
        ps[t * 64 + 2 * 16 + c] = __expf(v2 - lse);
        ps[t * 64 + 3 * 16 + c] = __expf(v3 - lse);
#pragma unroll
        for (int bf = 0; bf < 4; ++bf) {
          float l0 = acc[4 + bf][q], l1 = acc[8 + bf][q];
          float d01 = l0 - l1;
          pb[t * 64 + bf * 16 + c] = 1.f / (1.f + __expf(-d01));
          pc[t * 64 + bf * 16 + c] = 1.f / (1.f + __expf(d01));
        }
      }
    }
    return;
  }

  // ---------- act path (R10 structure) ----------
  const int abid = bid - 129;
  int swz = (abid & 7) * 512 + (abid >> 3);
  const int t0 = (swz >> 6) * 128;
  const int b0 = swz & 63;
  const int tbase = t0 + w * 32;

  // preload actions (8/thread)
  int act[2][4];
#pragma unroll
  for (int mf = 0; mf < 2; ++mf)
#pragma unroll
    for (int q = 0; q < 4; ++q)
      act[mf][q] = actions[tbase + mf * 16 + g * 4 + q];

  const u16* aRow0 = s_bf + (size_t)(tbase + c) * 256;
  const u16* aRow1 = s_bf + (size_t)(tbase + 16 + c) * 256;

  // batch 1: A fragments for ks 0..3
  bf16x8 af0[2][4];
#pragma unroll
  for (int ks = 0; ks < 4; ++ks) {
    af0[0][ks] = *(const bf16x8*)(aRow0 + ks * 32 + g * 8);
    af0[1][ks] = *(const bf16x8*)(aRow1 + ks * 32 + g * 8);
  }

  // stage B-group (64 rows x 256 k) into LDS, swizzled
  {
    const u16* bsrc = wa_t + (size_t)b0 * 64 * 256;
#pragma unroll
    for (int it = 0; it < 8; ++it) {
      int i = tid + 256 * it;
      int r = i >> 5, s = i & 31;
      ldsU[r * 32 + (s ^ (r & 7))] = *(const uint4*)(bsrc + r * 256 + s * 8);
    }
  }
  __syncthreads();

  f32x4 acc[2][4];
#pragma unroll
  for (int mf = 0; mf < 2; ++mf)
#pragma unroll
    for (int nf = 0; nf < 4; ++nf) acc[mf][nf] = (f32x4){0.f, 0.f, 0.f, 0.f};

  // batch 2: A fragments for ks 4..7 (latency hides under first compute half)
  bf16x8 af1[2][4];
#pragma unroll
  for (int ks = 0; ks < 4; ++ks) {
    af1[0][ks] = *(const bf16x8*)(aRow0 + 128 + ks * 32 + g * 8);
    af1[1][ks] = *(const bf16x8*)(aRow1 + 128 + ks * 32 + g * 8);
  }

  // compute: ks 0..3
#pragma unroll
  for (int ks = 0; ks < 4; ++ks) {
#pragma unroll
    for (int nf = 0; nf < 4; ++nf) {
      int rr = nf * 16 + c;
      bf16x8 bfv = *(const bf16x8*)&ldsU[rr * 32 + ((ks * 4 + g) ^ (rr & 7))];
      acc[0][nf] = __builtin_amdgcn_mfma_f32_16x16x32_bf16(af0[0][ks], bfv, acc[0][nf], 0, 0, 0);
      acc[1][nf] = __builtin_amdgcn_mfma_f32_16x16x32_bf16(af0[1][ks], bfv, acc[1][nf], 0, 0, 0);
    }
  }
  // compute: ks 4..7
#pragma unroll
  for (int ks = 0; ks < 4; ++ks) {
#pragma unroll
    for (int nf = 0; nf < 4; ++nf) {
      int rr = nf * 16 + c;
      bf16x8 bfv = *(const bf16x8*)&ldsU[rr * 32 + (((ks + 4) * 4 + g) ^ (rr & 7))];
      acc[0][nf] = __builtin_amdgcn_mfma_f32_16x16x32_bf16(af1[0][ks], bfv, acc[0][nf], 0, 0, 0);
      acc[1][nf] = __builtin_amdgcn_mfma_f32_16x16x32_bf16(af1[1][ks], bfv, acc[1][nf], 0, 0, 0);
    }
  }

  // epilogue: no-max softmax;  pe = exp(v_sel)/s; transposed coalesced writes
  const size_t pebase = (size_t)b0 * 8192;
#pragma unroll
  for (int mf = 0; mf < 2; ++mf) {
#pragma unroll
    for (int q = 0; q < 4; ++q) {
      float e0 = __expf(acc[mf][0][q]);
      float e1 = __expf(acc[mf][1][q]);
      float e2 = __expf(acc[mf][2][q]);
      float e3 = __expf(acc[mf][3][q]);
      float s = (e0 + e1) + (e2 + e3);
#pragma unroll
      for (int d = 1; d < 16; d <<= 1) s += __shfl_xor(s, d);
      int a = act[mf][q];
      int acf = a >> 4;
      float esel = (acf == 0) ? e0 : (acf == 1) ? e1 : (acf == 2) ? e2 : e3;
      if (c == (a & 15))
        peT[pebase + tbase + mf * 16 + g * 4 + q] = esel / s;
    }
  }
}

// ---------------- chunked scan: 4 waves per chunk ----------------
__global__ __launch_bounds__(256) void chunk_kernel(
    const float* __restrict__ peT, const float* __restrict__ ps,
    const float* __restrict__ pb, const float* __restrict__ pc,
    float* __restrict__ Mout, float* __restrict__ lscale) {
  __shared__ float scal[64 * 196];   // per step: [b(64) | ec(64) | es(64) | pad]
  __shared__ float part[2][256];
  __shared__ float mxs[4];
  const int ck = blockIdx.x;
  const int tid = threadIdx.x;
  const int lane = tid & 63;
  const int w = tid >> 6;
  const int tlo = ck * 64 + 1;

#pragma unroll
  for (int it = 0; it < 16; ++it) {
    int i = tid + 256 * it;
    int st = i >> 6, j = i & 63;
    int t = tlo + st;
    if (t <= T_LEN - 1) {
      int base = t * 64 + j;
      scal[st * 196 + j]       = pb[base];
      scal[st * 196 + 64 + j]  = pc[base];
      scal[st * 196 + 128 + j] = ps[base];
    } else {
      scal[st * 196 + j]       = 0.f;
      scal[st * 196 + 64 + j]  = 1.f;
      scal[st * 196 + 128 + j] = 0.f;
    }
  }
  __syncthreads();
#pragma unroll
  for (int it = 0; it < 16; ++it) {
    int i = tid + 256 * it;
    int j = i >> 6, st = i & 63;
    int t = tlo + st;
    if (t <= T_LEN - 1) {
      float e = peT[(size_t)j * 8192 + t];
      scal[st * 196 + 64 + j]  *= e;
      scal[st * 196 + 128 + j] *= e;
    }
  }
  __syncthreads();

  float M[16];
#pragma unroll
  for (int jj = 0; jj < 16; ++jj) M[jj] = ((w * 16 + jj) == lane) ? 1.f : 0.f;
  float lsc = 0.f;
  int pbuf = 0;

  for (int st = 0; st < 64; ++st) {
    const float* sb = &scal[st * 196];
    float p0 = 0.f, p1 = 0.f, p2 = 0.f, p3 = 0.f;
#pragma unroll
    for (int q = 0; q < 4; ++q) {
      float4 bq = *(const float4*)(sb + w * 16 + q * 4);
      p0 = fmaf(bq.x, M[q * 4 + 0], p0);
      p1 = fmaf(bq.y, M[q * 4 + 1], p1);
      p2 = fmaf(bq.z, M[q * 4 + 2], p2);
      p3 = fmaf(bq.w, M[q * 4 + 3], p3);
    }
    part[pbuf][w * 64 + lane] = (p0 + p1) + (p2 + p3);
    __syncthreads();
    float wv = part[pbuf][lane] + part[pbuf][64 + lane] +
               part[pbuf][128 + lane] + part[pbuf][192 + lane];
    pbuf ^= 1;
#pragma unroll
    for (int q = 0; q < 4; ++q) {
      float4 ecq = *(const float4*)(sb + 64 + w * 16 + q * 4);
      float4 esq = *(const float4*)(sb + 128 + w * 16 + q * 4);
      M[q * 4 + 0] = fmaf(ecq.x, M[q * 4 + 0], esq.x * wv);
      M[q * 4 + 1] = fmaf(ecq.y, M[q * 4 + 1], esq.y * wv);
      M[q * 4 + 2] = fmaf(ecq.z, M[q * 4 + 2], esq.z * wv);
      M[q * 4 + 3] = fmaf(ecq.w, M[q * 4 + 3], esq.w * wv);
    }
    if ((st & 7) == 7) {
      float mx = M[0];
#pragma unroll
      for (int jj = 1; jj < 16; ++jj) mx = fmaxf(mx, M[jj]);
#pragma unroll
      for (int d = 1; d < 64; d <<= 1) mx = fmaxf(mx, __shfl_xor(mx, d));
      if (lane == 0) mxs[w] = mx;
      __syncthreads();
      float bm = fmaxf(fmaxf(mxs[0], mxs[1]), fmaxf(mxs[2], mxs[3]));
      float inv = 1.f / bm;
#pragma unroll
      for (int jj = 0; jj < 16; ++jj) M[jj] *= inv;
      lsc += __logf(bm);
    }
  }

  float* out = Mout + (size_t)ck * 4096;
#pragma unroll
  for (int q = 0; q < 4; ++q) {
    float4 v = make_float4(M[q * 4 + 0], M[q * 4 + 1], M[q * 4 + 2], M[q * 4 + 3]);
    *(float4*)(out + lane * 64 + w * 16 + q * 4) = v;
  }
  if (tid == 0) lscale[ck] = lsc;
}

// ---------------- level-1 combine: 16 groups x 8 chunk matrices ----------------
__global__ __launch_bounds__(256) void group_combine(
    const float* __restrict__ Mout, const float* __restrict__ lscale,
    float* __restrict__ Gout, float* __restrict__ glsc) {
  const int g = blockIdx.x;
  const int tid = threadIdx.x;
  const int j = tid & 63;
  const int w = tid >> 6;
  __shared__ float Xa[64 * 68];
  __shared__ float Xb[64 * 68];
  __shared__ float Ma[64 * 68];
  __shared__ float Mb[64 * 68];
  __shared__ float red[4];

  {
    const float* M0 = Mout + (size_t)(8 * g) * 4096;
    const float* M1 = Mout + (size_t)(8 * g + 1) * 4096;
    for (int idx = tid; idx < 4096; idx += 256) {
      int i = idx >> 6, r = idx & 63;
      Xa[r * 68 + i] = M0[idx];
      Ma[i * 68 + r] = M1[idx];
    }
  }
  __syncthreads();

  float lsc = 0.f;
  float* Xcur = Xa; float* Xnxt = Xb;
  float* Mcur = Ma; float* Mnxt = Mb;

  for (int m = 1; m < 8; ++m) {
    float4 pf[4];
    if (m < 7) {
      const float* Mn = Mout + (size_t)(8 * g + m + 1) * 4096;
#pragma unroll
      for (int ii = 0; ii < 4; ++ii)
        pf[ii] = *(const float4*)(Mn + tid * 4 + 1024 * ii);
    }

    float acc[16];
#pragma unroll
    for (int i = 0; i < 16; ++i) acc[i] = 0.f;

#pragma unroll 4
    for (int k = 0; k < 64; ++k) {
      float mv = Mcur[k * 68 + j];
      const float* xr = Xcur + k * 68 + (w << 4);
      float4 x0 = *(const float4*)(xr + 0);
      float4 x1 = *(const float4*)(xr + 4);
      float4 x2 = *(const float4*)(xr + 8);
      float4 x3 = *(const float4*)(xr + 12);
      acc[0]  = fmaf(mv, x0.x, acc[0]);  acc[1]  = fmaf(mv, x0.y, acc[1]);
      acc[2]  = fmaf(mv, x0.z, acc[2]);  acc[3]  = fmaf(mv, x0.w, acc[3]);
      acc[4]  = fmaf(mv, x1.x, acc[4]);  acc[5]  = fmaf(mv, x1.y, acc[5]);
      acc[6]  = fmaf(mv, x1.z, acc[6]);  acc[7]  = fmaf(mv, x1.w, acc[7]);
      acc[8]  = fmaf(mv, x2.x, acc[8]);  acc[9]  = fmaf(mv, x2.y, acc[9]);
      acc[10] = fmaf(mv, x2.z, acc[10]); acc[11] = fmaf(mv, x2.w, acc[11]);
      acc[12] = fmaf(mv, x3.x, acc[12]); acc[13] = fmaf(mv, x3.y, acc[13]);
      acc[14] = fmaf(mv, x3.z, acc[14]); acc[15] = fmaf(mv, x3.w, acc[15]);
    }

    float lm = acc[0];
#pragma unroll
    for (int i = 1; i < 16; ++i) lm = fmaxf(lm, acc[i]);
#pragma unroll
    for (int d = 1; d < 64; d <<= 1) lm = fmaxf(lm, __shfl_xor(lm, d));
    if ((tid & 63) == 0) red[w] = lm;
    __syncthreads();
    float bm = fmaxf(fmaxf(red[0], red[1]), fmaxf(red[2], red[3]));
    float inv = 1.f / bm;
    lsc += __logf(bm);
#pragma unroll
    for (int i = 0; i < 16; ++i)
      Xnxt[j * 68 + (w << 4) + i] = acc[i] * inv;
    if (m < 7) {
#pragma unroll
      for (int ii = 0; ii < 4; ++ii) {
        int idx = tid * 4 + 1024 * ii;
        int k = idx >> 6, jj = idx & 63;
        *(float4*)(Mnxt + k * 68 + jj) = pf[ii];
      }
    }
    __syncthreads();
    float* t = Xcur; Xcur = Xnxt; Xnxt = t;
    float* tm = Mcur; Mcur = Mnxt; Mnxt = tm;
  }

  float* out = Gout + (size_t)g * 4096;
  for (int idx = tid; idx < 4096; idx += 256) {
    int i = idx >> 6, r = idx & 63;
    out[idx] = Xcur[r * 68 + i];
  }
  if (tid == 0) {
    float s = lsc;
#pragma unroll
    for (int m = 0; m < 8; ++m) s += lscale[8 * g + m];
    glsc[g] = s;
  }
}

// ---------------- level-2 combine: 16 sequential mat-vecs ----------------
__global__ __launch_bounds__(256) void final_combine(
    const float* __restrict__ Gout, const float* __restrict__ glsc,
    const float* __restrict__ peT, const float* __restrict__ ps,
    const float* __restrict__ pb, float* __restrict__ out) {
  const int tid = threadIdx.x;
  const int j = tid & 63, w = tid >> 6;
  __shared__ float vsh[64];
  __shared__ float part[4 * 64];
  if (tid < 64) vsh[tid] = ps[tid] * peT[(size_t)tid * 8192];   // f0
  __syncthreads();
  double lsc = 0.0;
  for (int gph = 0; gph < 16; ++gph) {
    const float* Gc = Gout + (size_t)gph * 4096;
    const int k0 = w << 4;
    float a0 = 0.f, a1 = 0.f, a2 = 0.f, a3 = 0.f;
#pragma unroll
    for (int kk = 0; kk < 16; kk += 4) {
      a0 = fmaf(vsh[k0 + kk + 0], Gc[(k0 + kk + 0) * 64 + j], a0);
      a1 = fmaf(vsh[k0 + kk + 1], Gc[(k0 + kk + 1) * 64 + j], a1);
      a2 = fmaf(vsh[k0 + kk + 2], Gc[(k0 + kk + 2) * 64 + j], a2);
      a3 = fmaf(vsh[k0 + kk + 3], Gc[(k0 + kk + 3) * 64 + j], a3);
    }
    part[w * 64 + j] = (a0 + a1) + (a2 + a3);
    __syncthreads();
    if (w == 0) {
      float u = part[j] + part[64 + j] + part[128 + j] + part[192 + j];
      float mx = u;
#pragma unroll
      for (int d = 1; d < 64; d <<= 1) mx = fmaxf(mx, __shfl_xor(mx, d));
      vsh[j] = u / mx;
      lsc += (double)__logf(mx) + (double)glsc[gph];
    }
    __syncthreads();
  }
  if (w == 0) {
    float z = vsh[j] * pb[T_LEN * 64 + j];
#pragma unroll
    for (int d = 1; d < 64; d <<= 1) z += __shfl_xor(z, d);
    if (j == 0) out[0] = (float)(-((double)logf(z) + lsc));
  }
}

extern "C" void kernel_launch(void* const* d_in, const int* in_sizes, int n_in,
                              void* d_out, int out_size, void* d_ws, size_t ws_size,
                              hipStream_t stream) {
  const float* s_i      = (const float*)d_in[0];
  const float* W_action = (const float*)d_in[1];
  const float* W_stop   = (const float*)d_in[2];
  const float* W_start  = (const float*)d_in[3];
  const int*   actions  = (const int*)d_in[4];

  char* ws = (char*)d_ws;
  u16*   s_bf  = (u16*)(ws + WS_SBF);
  u16*   wa_t  = (u16*)(ws + WS_WAT);
  u16*   wsm_t = (u16*)(ws + WS_WSMT);
  float* peT   = (float*)(ws + WS_PE);
  float* ps    = (float*)(ws + WS_PS);
  float* pb    = (float*)(ws + WS_PB);
  float* pc    = (float*)(ws + WS_PC);
  float* Mout  = (float*)(ws + WS_MOUT);
  float* lsc   = (float*)(ws + WS_LSC);
  float* Gout  = (float*)(ws + WS_GOUT);
  float* glsc  = (float*)(ws + WS_GLSC);

  conv_all<<<12544, 256, 0, stream>>>(s_i, W_action, W_stop, W_start, s_bf, wa_t, wsm_t);
  gemm_fused<<<4225, 256, 0, stream>>>(s_bf, wa_t, wsm_t, actions, peT, ps, pb, pc);
  chunk_kernel<<<128, 256, 0, stream>>>(peT, ps, pb, pc, Mout, lsc);
  group_combine<<<16, 256, 0, stream>>>(Mout, lsc, Gout, glsc);
  final_combine<<<1, 256, 0, stream>>>(Gout, glsc, peT, ps, pb, (float*)d_out);
}

// Round 16
// 131.040 us; speedup vs baseline: 1.3672x; 1.0368x over previous
//
#include <hip/hip_runtime.h>
#include <stdint.h>

// HMM trajectory-net forward:  -logsumexp over an 8191-step 64-state HMM scan.
// Pipeline (5 launches):
//   conv_all     : fused fp32 -> bf16 repacks (s_i, W_action, W_stop/start)
//   gemm_fused   : blocks 0..128 = start/stop GEMM (ps,pb,pc);
//                  blocks 129..4224 = action GEMM (B-group in LDS, A direct
//                  L2->VGPR, no mid-loop barriers, no-max softmax -> peT)
//   chunk_kernel : 128 chunks x 64 steps; k-split across lanes: wave owns 16
//                  columns, lane owns 16 rows of one column -> rank-1 term is
//                  2 shfl_xor, NO per-step barriers (barriers only at rescale)
//   group_combine: 16 blocks x 7 matmuls, LDS-resident, double-buffered prefetch
//   final_combine: 16 sequential mat-vecs + boundary terms -> scalar

typedef short bf16x8 __attribute__((ext_vector_type(8)));
typedef float f32x4  __attribute__((ext_vector_type(4)));
typedef unsigned short u16;

#define T_LEN 8192
#define SDIM  256

// ---- workspace layout (bytes) ----
#define WS_SBF    0              // 8256*256 bf16 (padded rows zeroed)
#define WS_WAT    4227072        // 4096*256 bf16  [b*64+n][s]
#define WS_WSMT   6324224        // 192*256 bf16   [col][s]
#define WS_PE     6422528        // peT: 64*8192 f32  [b][t]
#define WS_PS     8519680        // 8193*64 f32
#define WS_PB     10617088       // 8193*64 f32
#define WS_PC     12714496       // 8193*64 f32   (dead after chunk_kernel -> reused for Gout)
#define WS_MOUT   14811904       // 128*4096 f32  [chunk][k][j]
#define WS_LSC    16909056       // 128 f32
#define WS_GOUT   WS_PC                      // 16*4096 f32 (reuses pc region)
#define WS_GLSC   (WS_PC + 262144)           // 16 f32

__device__ inline u16 f2bf(float f) {
  union { float f; uint32_t u; } v; v.f = f;
  uint32_t u = v.u;
  return (u16)((u + 0x7fffu + ((u >> 16) & 1u)) >> 16);
}

// ---------------- fused converts ----------------
__global__ void conv_all(const float* __restrict__ s_i, const float* __restrict__ Wa,
                         const float* __restrict__ Wstop, const float* __restrict__ Wstart,
                         u16* __restrict__ s_bf, u16* __restrict__ wa_t,
                         u16* __restrict__ wsm_t) {
  const int bid = blockIdx.x;
  const int tid = threadIdx.x;
  if (bid < 8256) {                       // s_i -> s_bf (padded)
    int idx = bid * 256 + tid;
    int t = idx >> 8;
    float v = (t < T_LEN + 1) ? s_i[idx] : 0.f;
    s_bf[idx] = f2bf(v);
  } else if (bid < 8256 + 4096) {         // W_action -> wa_t (transposed)
    int idx = (bid - 8256) * 256 + tid;
    int s = idx >> 12, bn = idx & 4095;
    wa_t[bn * 256 + s] = f2bf(Wa[idx]);
  } else {                                // W_stop/W_start -> wsm_t
    int idx = (bid - 12352) * 256 + tid;
    int col = idx >> 8, s = idx & 255;
    float v;
    if (col < 64)       v = Wstart[s * 64 + col];
    else if (col < 128) v = Wstop[s * 128 + (col - 64) * 2 + 0];
    else                v = Wstop[s * 128 + (col - 128) * 2 + 1];
    wsm_t[col * 256 + s] = f2bf(v);
  }
}

// ---------------- fused GEMMs ----------------
__global__ __launch_bounds__(256, 4) void gemm_fused(
    const u16* __restrict__ s_bf, const u16* __restrict__ wa_t,
    const u16* __restrict__ wsm_t, const int* __restrict__ actions,
    float* __restrict__ peT, float* __restrict__ ps,
    float* __restrict__ pb, float* __restrict__ pc) {
  __shared__ uint4 ldsU[64 * 32];   // 32KB, shared by both paths
  const int tid = threadIdx.x;
  const int lane = tid & 63;
  const int w = tid >> 6;
  const int g = lane >> 4, c = lane & 15;
  const int bid = blockIdx.x;

  if (bid < 129) {
    // ---------- small path: start/stop logits + softmax/sigmoid ----------
    uint4* sA = ldsU;          // 64 rows x 8 slots
    uint4* sB = ldsU + 512;    // 192 rows x 8 slots
    const int t0 = bid * 64;

    f32x4 acc[12];
#pragma unroll
    for (int i = 0; i < 12; ++i) acc[i] = (f32x4){0.f, 0.f, 0.f, 0.f};

    for (int kq = 0; kq < 4; ++kq) {
      if (kq) __syncthreads();
#pragma unroll
      for (int i = tid; i < 512; i += 256) {
        int row = i >> 3, u = i & 7;
        sA[row * 8 + (u ^ (row & 7))] =
            *(const uint4*)(s_bf + (size_t)(t0 + row) * 256 + kq * 64 + u * 8);
      }
#pragma unroll
      for (int i = tid; i < 1536; i += 256) {
        int row = i >> 3, u = i & 7;
        sB[row * 8 + (u ^ (row & 7))] =
            *(const uint4*)(wsm_t + (size_t)row * 256 + kq * 64 + u * 8);
      }
      __syncthreads();
#pragma unroll
      for (int kk = 0; kk < 2; ++kk) {
        int u = kk * 4 + g;
        int arow = w * 16 + c;
        bf16x8 af = *(const bf16x8*)&sA[arow * 8 + (u ^ (arow & 7))];
#pragma unroll
        for (int cf = 0; cf < 12; ++cf) {
          int brow = cf * 16 + c;
          bf16x8 bfr = *(const bf16x8*)&sB[brow * 8 + (u ^ (brow & 7))];
          acc[cf] = __builtin_amdgcn_mfma_f32_16x16x32_bf16(af, bfr, acc[cf], 0, 0, 0);
        }
      }
    }

#pragma unroll
    for (int q = 0; q < 4; ++q) {
      int t = t0 + w * 16 + g * 4 + q;
      float v0 = acc[0][q], v1 = acc[1][q], v2 = acc[2][q], v3 = acc[3][q];
      float m = fmaxf(fmaxf(v0, v1), fmaxf(v2, v3));
#pragma unroll
      for (int d = 1; d < 16; d <<= 1) m = fmaxf(m, __shfl_xor(m, d));
      float s = __expf(v0 - m) + __expf(v1 - m) + __expf(v2 - m) + __expf(v3 - m);
#pragma unroll
      for (int d = 1; d < 16; d <<= 1) s += __shfl_xor(s, d);
      float lse = m + __logf(s);
      if (t <= T_LEN) {
        ps[t * 64 + 0 * 16 + c] = __expf(v0 - lse);
        ps[t * 64 + 1 * 16 + c] = __expf(v1 - lse);
        ps[t * 64 + 2 * 16 + c] = __expf(v2 - lse);
        ps[t * 64 + 3 * 16 + c] = __expf(v3 - lse);
#pragma unroll
        for (int bf = 0; bf < 4; ++bf) {
          float l0 = acc[4 + bf][q], l1 = acc[8 + bf][q];
          float d01 = l0 - l1;
          pb[t * 64 + bf * 16 + c] = 1.f / (1.f + __expf(-d01));
          pc[t * 64 + bf * 16 + c] = 1.f / (1.f + __expf(d01));
        }
      }
    }
    return;
  }

  // ---------- act path ----------
  const int abid = bid - 129;
  int swz = (abid & 7) * 512 + (abid >> 3);
  const int t0 = (swz >> 6) * 128;
  const int b0 = swz & 63;
  const int tbase = t0 + w * 32;

  int act[2][4];
#pragma unroll
  for (int mf = 0; mf < 2; ++mf)
#pragma unroll
    for (int q = 0; q < 4; ++q)
      act[mf][q] = actions[tbase + mf * 16 + g * 4 + q];

  const u16* aRow0 = s_bf + (size_t)(tbase + c) * 256;
  const u16* aRow1 = s_bf + (size_t)(tbase + 16 + c) * 256;

  bf16x8 af0[2][4];
#pragma unroll
  for (int ks = 0; ks < 4; ++ks) {
    af0[0][ks] = *(const bf16x8*)(aRow0 + ks * 32 + g * 8);
    af0[1][ks] = *(const bf16x8*)(aRow1 + ks * 32 + g * 8);
  }

  {
    const u16* bsrc = wa_t + (size_t)b0 * 64 * 256;
#pragma unroll
    for (int it = 0; it < 8; ++it) {
      int i = tid + 256 * it;
      int r = i >> 5, s = i & 31;
      ldsU[r * 32 + (s ^ (r & 7))] = *(const uint4*)(bsrc + r * 256 + s * 8);
    }
  }
  __syncthreads();

  f32x4 acc[2][4];
#pragma unroll
  for (int mf = 0; mf < 2; ++mf)
#pragma unroll
    for (int nf = 0; nf < 4; ++nf) acc[mf][nf] = (f32x4){0.f, 0.f, 0.f, 0.f};

  bf16x8 af1[2][4];
#pragma unroll
  for (int ks = 0; ks < 4; ++ks) {
    af1[0][ks] = *(const bf16x8*)(aRow0 + 128 + ks * 32 + g * 8);
    af1[1][ks] = *(const bf16x8*)(aRow1 + 128 + ks * 32 + g * 8);
  }

#pragma unroll
  for (int ks = 0; ks < 4; ++ks) {
#pragma unroll
    for (int nf = 0; nf < 4; ++nf) {
      int rr = nf * 16 + c;
      bf16x8 bfv = *(const bf16x8*)&ldsU[rr * 32 + ((ks * 4 + g) ^ (rr & 7))];
      acc[0][nf] = __builtin_amdgcn_mfma_f32_16x16x32_bf16(af0[0][ks], bfv, acc[0][nf], 0, 0, 0);
      acc[1][nf] = __builtin_amdgcn_mfma_f32_16x16x32_bf16(af0[1][ks], bfv, acc[1][nf], 0, 0, 0);
    }
  }
#pragma unroll
  for (int ks = 0; ks < 4; ++ks) {
#pragma unroll
    for (int nf = 0; nf < 4; ++nf) {
      int rr = nf * 16 + c;
      bf16x8 bfv = *(const bf16x8*)&ldsU[rr * 32 + (((ks + 4) * 4 + g) ^ (rr & 7))];
      acc[0][nf] = __builtin_amdgcn_mfma_f32_16x16x32_bf16(af1[0][ks], bfv, acc[0][nf], 0, 0, 0);
      acc[1][nf] = __builtin_amdgcn_mfma_f32_16x16x32_bf16(af1[1][ks], bfv, acc[1][nf], 0, 0, 0);
    }
  }

  const size_t pebase = (size_t)b0 * 8192;
#pragma unroll
  for (int mf = 0; mf < 2; ++mf) {
#pragma unroll
    for (int q = 0; q < 4; ++q) {
      float e0 = __expf(acc[mf][0][q]);
      float e1 = __expf(acc[mf][1][q]);
      float e2 = __expf(acc[mf][2][q]);
      float e3 = __expf(acc[mf][3][q]);
      float s = (e0 + e1) + (e2 + e3);
#pragma unroll
      for (int d = 1; d < 16; d <<= 1) s += __shfl_xor(s, d);
      int a = act[mf][q];
      int acf = a >> 4;
      float esel = (acf == 0) ? e0 : (acf == 1) ? e1 : (acf == 2) ? e2 : e3;
      if (c == (a & 15))
        peT[pebase + tbase + mf * 16 + g * 4 + q] = esel / s;
    }
  }
}

// ---------------- chunked scan: k-split, barrier-free step loop ----------------
// Wave w owns columns [w*16, w*16+16); lane L owns rows [(L&3)*16, +16) of
// column w*16 + (L>>2).  wv[k] = 16 local fma + 2 shfl_xor (lanes sharing a
// column differ in bits 0-1).  NO barriers in the 64-step loop; barriers only
// at the 8 rescales (block-uniform scale).  Scalars staged in LDS as before.
__global__ __launch_bounds__(256) void chunk_kernel(
    const float* __restrict__ peT, const float* __restrict__ ps,
    const float* __restrict__ pb, const float* __restrict__ pc,
    float* __restrict__ Mout, float* __restrict__ lscale) {
  __shared__ float scal[64 * 196];   // per step: [b(64) | ec(64) | es(64) | pad]
  __shared__ float mxs[4];
  const int ck = blockIdx.x;
  const int tid = threadIdx.x;
  const int lane = tid & 63;
  const int w = tid >> 6;
  const int tlo = ck * 64 + 1;

  // staging pass 1: b, c, s from [t][64] arrays (coalesced)
#pragma unroll
  for (int it = 0; it < 16; ++it) {
    int i = tid + 256 * it;
    int st = i >> 6, j = i & 63;
    int t = tlo + st;
    if (t <= T_LEN - 1) {
      int base = t * 64 + j;
      scal[st * 196 + j]       = pb[base];
      scal[st * 196 + 64 + j]  = pc[base];
      scal[st * 196 + 128 + j] = ps[base];
    } else {
      scal[st * 196 + j]       = 0.f;
      scal[st * 196 + 64 + j]  = 1.f;
      scal[st * 196 + 128 + j] = 0.f;
    }
  }
  __syncthreads();
  // staging pass 2: fold e from peT[b][t] (coalesced on that layout)
#pragma unroll
  for (int it = 0; it < 16; ++it) {
    int i = tid + 256 * it;
    int j = i >> 6, st = i & 63;
    int t = tlo + st;
    if (t <= T_LEN - 1) {
      float e = peT[(size_t)j * 8192 + t];
      scal[st * 196 + 64 + j]  *= e;
      scal[st * 196 + 128 + j] *= e;
    }
  }
  __syncthreads();

  const int kcol = w * 16 + (lane >> 2);   // column this lane owns
  const int roff = (lane & 3) * 16;        // first row this lane owns

  float M[16];
#pragma unroll
  for (int jj = 0; jj < 16; ++jj) M[jj] = ((roff + jj) == kcol) ? 1.f : 0.f;
  float lsc = 0.f;

  for (int st8 = 0; st8 < 8; ++st8) {
#pragma unroll
    for (int s8 = 0; s8 < 8; ++s8) {
      const float* sb = &scal[(st8 * 8 + s8) * 196];
      // partial of wv over this lane's 16 rows
      float4 b0 = *(const float4*)(sb + roff + 0);
      float4 b1 = *(const float4*)(sb + roff + 4);
      float4 b2 = *(const float4*)(sb + roff + 8);
      float4 b3 = *(const float4*)(sb + roff + 12);
      float p0 = 0.f, p1 = 0.f, p2 = 0.f, p3 = 0.f;
      p0 = fmaf(b0.x, M[0], p0);  p1 = fmaf(b0.y, M[1], p1);
      p2 = fmaf(b0.z, M[2], p2);  p3 = fmaf(b0.w, M[3], p3);
      p0 = fmaf(b1.x, M[4], p0);  p1 = fmaf(b1.y, M[5], p1);
      p2 = fmaf(b1.z, M[6], p2);  p3 = fmaf(b1.w, M[7], p3);
      p0 = fmaf(b2.x, M[8], p0);  p1 = fmaf(b2.y, M[9], p1);
      p2 = fmaf(b2.z, M[10], p2); p3 = fmaf(b2.w, M[11], p3);
      p0 = fmaf(b3.x, M[12], p0); p1 = fmaf(b3.y, M[13], p1);
      p2 = fmaf(b3.z, M[14], p2); p3 = fmaf(b3.w, M[15], p3);
      float p = (p0 + p1) + (p2 + p3);
      p += __shfl_xor(p, 1);
      p += __shfl_xor(p, 2);     // p == wv[kcol], uniform over the 4 row-lanes
      // update M
      float4 e0 = *(const float4*)(sb + 64 + roff + 0);
      float4 e1 = *(const float4*)(sb + 64 + roff + 4);
      float4 e2 = *(const float4*)(sb + 64 + roff + 8);
      float4 e3 = *(const float4*)(sb + 64 + roff + 12);
      float4 s0 = *(const float4*)(sb + 128 + roff + 0);
      float4 s1 = *(const float4*)(sb + 128 + roff + 4);
      float4 s2 = *(const float4*)(sb + 128 + roff + 8);
      float4 s3 = *(const float4*)(sb + 128 + roff + 12);
      M[0]  = fmaf(e0.x, M[0],  s0.x * p);  M[1]  = fmaf(e0.y, M[1],  s0.y * p);
      M[2]  = fmaf(e0.z, M[2],  s0.z * p);  M[3]  = fmaf(e0.w, M[3],  s0.w * p);
      M[4]  = fmaf(e1.x, M[4],  s1.x * p);  M[5]  = fmaf(e1.y, M[5],  s1.y * p);
      M[6]  = fmaf(e1.z, M[6],  s1.z * p);  M[7]  = fmaf(e1.w, M[7],  s1.w * p);
      M[8]  = fmaf(e2.x, M[8],  s2.x * p);  M[9]  = fmaf(e2.y, M[9],  s2.y * p);
      M[10] = fmaf(e2.z, M[10], s2.z * p);  M[11] = fmaf(e2.w, M[11], s2.w * p);
      M[12] = fmaf(e3.x, M[12], s3.x * p);  M[13] = fmaf(e3.y, M[13], s3.y * p);
      M[14] = fmaf(e3.z, M[14], s3.z * p);  M[15] = fmaf(e3.w, M[15], s3.w * p);
    }
    // block-uniform rescale (entries all >= 0)
    float mx = M[0];
#pragma unroll
    for (int jj = 1; jj < 16; ++jj) mx = fmaxf(mx, M[jj]);
#pragma unroll
    for (int d = 1; d < 64; d <<= 1) mx = fmaxf(mx, __shfl_xor(mx, d));
    if (lane == 0) mxs[w] = mx;
    __syncthreads();
    float bm = fmaxf(fmaxf(mxs[0], mxs[1]), fmaxf(mxs[2], mxs[3]));
    float inv = 1.f / bm;
#pragma unroll
    for (int jj = 0; jj < 16; ++jj) M[jj] *= inv;
    lsc += __logf(bm);
    __syncthreads();   // protect mxs before next rescale's write
  }

  // write out: Mout[ck][i=kcol][j=row] = M[row][kcol]  (64B contiguous per lane)
  float* out = Mout + (size_t)ck * 4096 + kcol * 64 + roff;
  *(float4*)(out + 0)  = make_float4(M[0],  M[1],  M[2],  M[3]);
  *(float4*)(out + 4)  = make_float4(M[4],  M[5],  M[6],  M[7]);
  *(float4*)(out + 8)  = make_float4(M[8],  M[9],  M[10], M[11]);
  *(float4*)(out + 12) = make_float4(M[12], M[13], M[14], M[15]);
  if (tid == 0) lscale[ck] = lsc;
}

// ---------------- level-1 combine: 16 groups x 8 chunk matrices ----------------
__global__ __launch_bounds__(256) void group_combine(
    const float* __restrict__ Mout, const float* __restrict__ lscale,
    float* __restrict__ Gout, float* __restrict__ glsc) {
  const int g = blockIdx.x;
  const int tid = threadIdx.x;
  const int j = tid & 63;
  const int w = tid >> 6;
  __shared__ float Xa[64 * 68];
  __shared__ float Xb[64 * 68];
  __shared__ float Ma[64 * 68];
  __shared__ float Mb[64 * 68];
  __shared__ float red[4];

  {
    const float* M0 = Mout + (size_t)(8 * g) * 4096;
    const float* M1 = Mout + (size_t)(8 * g + 1) * 4096;
    for (int idx = tid; idx < 4096; idx += 256) {
      int i = idx >> 6, r = idx & 63;
      Xa[r * 68 + i] = M0[idx];
      Ma[i * 68 + r] = M1[idx];
    }
  }
  __syncthreads();

  float lsc = 0.f;
  float* Xcur = Xa; float* Xnxt = Xb;
  float* Mcur = Ma; float* Mnxt = Mb;

  for (int m = 1; m < 8; ++m) {
    float4 pf[4];
    if (m < 7) {
      const float* Mn = Mout + (size_t)(8 * g + m + 1) * 4096;
#pragma unroll
      for (int ii = 0; ii < 4; ++ii)
        pf[ii] = *(const float4*)(Mn + tid * 4 + 1024 * ii);
    }

    float acc[16];
#pragma unroll
    for (int i = 0; i < 16; ++i) acc[i] = 0.f;

#pragma unroll 4
    for (int k = 0; k < 64; ++k) {
      float mv = Mcur[k * 68 + j];
      const float* xr = Xcur + k * 68 + (w << 4);
      float4 x0 = *(const float4*)(xr + 0);
      float4 x1 = *(const float4*)(xr + 4);
      float4 x2 = *(const float4*)(xr + 8);
      float4 x3 = *(const float4*)(xr + 12);
      acc[0]  = fmaf(mv, x0.x, acc[0]);  acc[1]  = fmaf(mv, x0.y, acc[1]);
      acc[2]  = fmaf(mv, x0.z, acc[2]);  acc[3]  = fmaf(mv, x0.w, acc[3]);
      acc[4]  = fmaf(mv, x1.x, acc[4]);  acc[5]  = fmaf(mv, x1.y, acc[5]);
      acc[6]  = fmaf(mv, x1.z, acc[6]);  acc[7]  = fmaf(mv, x1.w, acc[7]);
      acc[8]  = fmaf(mv, x2.x, acc[8]);  acc[9]  = fmaf(mv, x2.y, acc[9]);
      acc[10] = fmaf(mv, x2.z, acc[10]); acc[11] = fmaf(mv, x2.w, acc[11]);
      acc[12] = fmaf(mv, x3.x, acc[12]); acc[13] = fmaf(mv, x3.y, acc[13]);
      acc[14] = fmaf(mv, x3.z, acc[14]); acc[15] = fmaf(mv, x3.w, acc[15]);
    }

    float lm = acc[0];
#pragma unroll
    for (int i = 1; i < 16; ++i) lm = fmaxf(lm, acc[i]);
#pragma unroll
    for (int d = 1; d < 64; d <<= 1) lm = fmaxf(lm, __shfl_xor(lm, d));
    if ((tid & 63) == 0) red[w] = lm;
    __syncthreads();
    float bm = fmaxf(fmaxf(red[0], red[1]), fmaxf(red[2], red[3]));
    float inv = 1.f / bm;
    lsc += __logf(bm);
#pragma unroll
    for (int i = 0; i < 16; ++i)
      Xnxt[j * 68 + (w << 4) + i] = acc[i] * inv;
    if (m < 7) {
#pragma unroll
      for (int ii = 0; ii < 4; ++ii) {
        int idx = tid * 4 + 1024 * ii;
        int k = idx >> 6, jj = idx & 63;
        *(float4*)(Mnxt + k * 68 + jj) = pf[ii];
      }
    }
    __syncthreads();
    float* t = Xcur; Xcur = Xnxt; Xnxt = t;
    float* tm = Mcur; Mcur = Mnxt; Mnxt = tm;
  }

  float* out = Gout + (size_t)g * 4096;
  for (int idx = tid; idx < 4096; idx += 256) {
    int i = idx >> 6, r = idx & 63;
    out[idx] = Xcur[r * 68 + i];
  }
  if (tid == 0) {
    float s = lsc;
#pragma unroll
    for (int m = 0; m < 8; ++m) s += lscale[8 * g + m];
    glsc[g] = s;
  }
}

// ---------------- level-2 combine: 16 sequential mat-vecs ----------------
__global__ __launch_bounds__(256) void final_combine(
    const float* __restrict__ Gout, const float* __restrict__ glsc,
    const float* __restrict__ peT, const float* __restrict__ ps,
    const float* __restrict__ pb, float* __restrict__ out) {
  const int tid = threadIdx.x;
  const int j = tid & 63, w = tid >> 6;
  __shared__ float vsh[64];
  __shared__ float part[4 * 64];
  if (tid < 64) vsh[tid] = ps[tid] * peT[(size_t)tid * 8192];   // f0
  __syncthreads();
  double lsc = 0.0;
  for (int gph = 0; gph < 16; ++gph) {
    const float* Gc = Gout + (size_t)gph * 4096;
    const int k0 = w << 4;
    float a0 = 0.f, a1 = 0.f, a2 = 0.f, a3 = 0.f;
#pragma unroll
    for (int kk = 0; kk < 16; kk += 4) {
      a0 = fmaf(vsh[k0 + kk + 0], Gc[(k0 + kk + 0) * 64 + j], a0);
      a1 = fmaf(vsh[k0 + kk + 1], Gc[(k0 + kk + 1) * 64 + j], a1);
      a2 = fmaf(vsh[k0 + kk + 2], Gc[(k0 + kk + 2) * 64 + j], a2);
      a3 = fmaf(vsh[k0 + kk + 3], Gc[(k0 + kk + 3) * 64 + j], a3);
    }
    part[w * 64 + j] = (a0 + a1) + (a2 + a3);
    __syncthreads();
    if (w == 0) {
      float u = part[j] + part[64 + j] + part[128 + j] + part[192 + j];
      float mx = u;
#pragma unroll
      for (int d = 1; d < 64; d <<= 1) mx = fmaxf(mx, __shfl_xor(mx, d));
      vsh[j] = u / mx;
      lsc += (double)__logf(mx) + (double)glsc[gph];
    }
    __syncthreads();
  }
  if (w == 0) {
    float z = vsh[j] * pb[T_LEN * 64 + j];
#pragma unroll
    for (int d = 1; d < 64; d <<= 1) z += __shfl_xor(z, d);
    if (j == 0) out[0] = (float)(-((double)logf(z) + lsc));
  }
}

extern "C" void kernel_launch(void* const* d_in, const int* in_sizes, int n_in,
                              void* d_out, int out_size, void* d_ws, size_t ws_size,
                              hipStream_t stream) {
  const float* s_i      = (const float*)d_in[0];
  const float* W_action = (const float*)d_in[1];
  const float* W_stop   = (const float*)d_in[2];
  const float* W_start  = (const float*)d_in[3];
  const int*   actions  = (const int*)d_in[4];

  char* ws = (char*)d_ws;
  u16*   s_bf  = (u16*)(ws + WS_SBF);
  u16*   wa_t  = (u16*)(ws + WS_WAT);
  u16*   wsm_t = (u16*)(ws + WS_WSMT);
  float* peT   = (float*)(ws + WS_PE);
  float* ps    = (float*)(ws + WS_PS);
  float* pb    = (float*)(ws + WS_PB);
  float* pc    = (float*)(ws + WS_PC);
  float* Mout  = (float*)(ws + WS_MOUT);
  float* lsc   = (float*)(ws + WS_LSC);
  float* Gout  = (float*)(ws + WS_GOUT);
  float* glsc  = (float*)(ws + WS_GLSC);

  conv_all<<<12544, 256, 0, stream>>>(s_i, W_action, W_stop, W_start, s_bf, wa_t, wsm_t);
  gemm_fused<<<4225, 256, 0, stream>>>(s_bf, wa_t, wsm_t, actions, peT, ps, pb, pc);
  chunk_kernel<<<128, 256, 0, stream>>>(peT, ps, pb, pc, Mout, lsc);
  group_combine<<<16, 256, 0, stream>>>(Mout, lsc, Gout, glsc);
  final_combine<<<1, 256, 0, stream>>>(Gout, glsc, peT, ps, pb, (float*)d_out);
}

// Round 17
// 125.540 us; speedup vs baseline: 1.4271x; 1.0438x over previous
//
#include <hip/hip_runtime.h>
#include <stdint.h>

// HMM trajectory-net forward:  -logsumexp over an 8191-step 64-state HMM scan.
// Pipeline (5 launches):
//   conv_all     : fused fp32 -> bf16 repacks; s_i vectorized x4; W_action
//                  transposed via 64x64 LDS tiles (coalesced both sides)
//   gemm_fused   : blocks 0..128 = start/stop GEMM (ps,pb,pc);
//                  blocks 129..4224 = action GEMM (B-group in LDS, A direct
//                  L2->VGPR, no mid-loop barriers, no-max softmax -> peT)
//   chunk_kernel : 128 chunks x 64 steps; k-split across lanes, barrier-free
//   group_combine: 16 blocks x 7 matmuls, LDS-resident, double-buffered prefetch
//   final_combine: 16 sequential mat-vecs + boundary terms -> scalar

typedef short bf16x8 __attribute__((ext_vector_type(8)));
typedef float f32x4  __attribute__((ext_vector_type(4)));
typedef unsigned short u16;

#define T_LEN 8192
#define SDIM  256

// ---- workspace layout (bytes) ----
#define WS_SBF    0              // 8256*256 bf16 (padded rows zeroed)
#define WS_WAT    4227072        // 4096*256 bf16  [b*64+n][s]
#define WS_WSMT   6324224        // 192*256 bf16   [col][s]
#define WS_PE     6422528        // peT: 64*8192 f32  [b][t]
#define WS_PS     8519680        // 8193*64 f32
#define WS_PB     10617088       // 8193*64 f32
#define WS_PC     12714496       // 8193*64 f32   (dead after chunk_kernel -> reused for Gout)
#define WS_MOUT   14811904       // 128*4096 f32  [chunk][k][j]
#define WS_LSC    16909056       // 128 f32
#define WS_GOUT   WS_PC                      // 16*4096 f32 (reuses pc region)
#define WS_GLSC   (WS_PC + 262144)           // 16 f32

__device__ inline u16 f2bf(float f) {
  union { float f; uint32_t u; } v; v.f = f;
  uint32_t u = v.u;
  return (u16)((u + 0x7fffu + ((u >> 16) & 1u)) >> 16);
}

// ---------------- fused converts ----------------
// blocks [0, 2064)   : s_i -> s_bf, 4 elems/thread (float4 -> ushort4)
// blocks [2064, 2320): W_action transpose via 64x64 LDS tile, coalesced R+W
// blocks [2320, 2512): W_stop/W_start -> wsm_t (small)
__global__ void conv_all(const float* __restrict__ s_i, const float* __restrict__ Wa,
                         const float* __restrict__ Wstop, const float* __restrict__ Wstart,
                         u16* __restrict__ s_bf, u16* __restrict__ wa_t,
                         u16* __restrict__ wsm_t) {
  __shared__ u16 tile[64 * 65];
  const int bid = blockIdx.x;
  const int tid = threadIdx.x;
  if (bid < 2064) {                       // s_i -> s_bf (padded), x4 vectorized
    int idx = (bid * 256 + tid) * 4;
    int t = idx >> 8;
    ushort4 o;
    if (t < T_LEN + 1) {
      float4 v = *(const float4*)(s_i + idx);
      o = make_ushort4(f2bf(v.x), f2bf(v.y), f2bf(v.z), f2bf(v.w));
    } else {
      o = make_ushort4(0, 0, 0, 0);
    }
    *(ushort4*)(s_bf + idx) = o;
  } else if (bid < 2320) {                // W_action [s][bn] -> wa_t [bn][s]
    int tb = bid - 2064;                  // 0..255
    int s0 = (tb >> 6) * 64;              // 4 s-tiles
    int bn0 = (tb & 63) * 64;             // 64 bn-tiles
    // read 64(s) x 64(bn), coalesced over bn
#pragma unroll
    for (int it = 0; it < 16; ++it) {
      int i = tid + 256 * it;
      int r = i >> 6, cc = i & 63;        // r = s-off, cc = bn-off
      tile[r * 65 + cc] = f2bf(Wa[(size_t)(s0 + r) * 4096 + bn0 + cc]);
    }
    __syncthreads();
    // write 64(bn) x 64(s), coalesced over s
#pragma unroll
    for (int it = 0; it < 16; ++it) {
      int i = tid + 256 * it;
      int r = i >> 6, cc = i & 63;        // r = bn-off, cc = s-off
      wa_t[(size_t)(bn0 + r) * 256 + s0 + cc] = tile[cc * 65 + r];
    }
  } else {                                // W_stop/W_start -> wsm_t
    int idx = (bid - 2320) * 256 + tid;
    int col = idx >> 8, s = idx & 255;
    float v;
    if (col < 64)       v = Wstart[s * 64 + col];
    else if (col < 128) v = Wstop[s * 128 + (col - 64) * 2 + 0];
    else                v = Wstop[s * 128 + (col - 128) * 2 + 1];
    wsm_t[col * 256 + s] = f2bf(v);
  }
}

// ---------------- fused GEMMs ----------------
__global__ __launch_bounds__(256, 4) void gemm_fused(
    const u16* __restrict__ s_bf, const u16* __restrict__ wa_t,
    const u16* __restrict__ wsm_t, const int* __restrict__ actions,
    float* __restrict__ peT, float* __restrict__ ps,
    float* __restrict__ pb, float* __restrict__ pc) {
  __shared__ uint4 ldsU[64 * 32];   // 32KB, shared by both paths
  const int tid = threadIdx.x;
  const int lane = tid & 63;
  const int w = tid >> 6;
  const int g = lane >> 4, c = lane & 15;
  const int bid = blockIdx.x;

  if (bid < 129) {
    // ---------- small path: start/stop logits + softmax/sigmoid ----------
    uint4* sA = ldsU;          // 64 rows x 8 slots
    uint4* sB = ldsU + 512;    // 192 rows x 8 slots
    const int t0 = bid * 64;

    f32x4 acc[12];
#pragma unroll
    for (int i = 0; i < 12; ++i) acc[i] = (f32x4){0.f, 0.f, 0.f, 0.f};

    for (int kq = 0; kq < 4; ++kq) {
      if (kq) __syncthreads();
#pragma unroll
      for (int i = tid; i < 512; i += 256) {
        int row = i >> 3, u = i & 7;
        sA[row * 8 + (u ^ (row & 7))] =
            *(const uint4*)(s_bf + (size_t)(t0 + row) * 256 + kq * 64 + u * 8);
      }
#pragma unroll
      for (int i = tid; i < 1536; i += 256) {
        int row = i >> 3, u = i & 7;
        sB[row * 8 + (u ^ (row & 7))] =
            *(const uint4*)(wsm_t + (size_t)row * 256 + kq * 64 + u * 8);
      }
      __syncthreads();
#pragma unroll
      for (int kk = 0; kk < 2; ++kk) {
        int u = kk * 4 + g;
        int arow = w * 16 + c;
        bf16x8 af = *(const bf16x8*)&sA[arow * 8 + (u ^ (arow & 7))];
#pragma unroll
        for (int cf = 0; cf < 12; ++cf) {
          int brow = cf * 16 + c;
          bf16x8 bfr = *(const bf16x8*)&sB[brow * 8 + (u ^ (brow & 7))];
          acc[cf] = __builtin_amdgcn_mfma_f32_16x16x32_bf16(af, bfr, acc[cf], 0, 0, 0);
        }
      }
    }

#pragma unroll
    for (int q = 0; q < 4; ++q) {
      int t = t0 + w * 16 + g * 4 + q;
      float v0 = acc[0][q], v1 = acc[1][q], v2 = acc[2][q], v3 = acc[3][q];
      float m = fmaxf(fmaxf(v0, v1), fmaxf(v2, v3));
#pragma unroll
      for (int d = 1; d < 16; d <<= 1) m = fmaxf(m, __shfl_xor(m, d));
      float s = __expf(v0 - m) + __expf(v1 - m) + __expf(v2 - m) + __expf(v3 - m);
#pragma unroll
      for (int d = 1; d < 16; d <<= 1) s += __shfl_xor(s, d);
      float lse = m + __logf(s);
      if (t <= T_LEN) {
        ps[t * 64 + 0 * 16 + c] = __expf(v0 - lse);
        ps[t * 64 + 1 * 16 + c] = __expf(v1 - lse);
        ps[t * 64 + 2 * 16 + c] = __expf(v2 - lse);
        ps[t * 64 + 3 * 16 + c] = __expf(v3 - lse);
#pragma unroll
        for (int bf = 0; bf < 4; ++bf) {
          float l0 = acc[4 + bf][q], l1 = acc[8 + bf][q];
          float d01 = l0 - l1;
          pb[t * 64 + bf * 16 + c] = 1.f / (1.f + __expf(-d01));
          pc[t * 64 + bf * 16 + c] = 1.f / (1.f + __expf(d01));
        }
      }
    }
    return;
  }

  // ---------- act path ----------
  const int abid = bid - 129;
  int swz = (abid & 7) * 512 + (abid >> 3);
  const int t0 = (swz >> 6) * 128;
  const int b0 = swz & 63;
  const int tbase = t0 + w * 32;

  int act[2][4];
#pragma unroll
  for (int mf = 0; mf < 2; ++mf)
#pragma unroll
    for (int q = 0; q < 4; ++q)
      act[mf][q] = actions[tbase + mf * 16 + g * 4 + q];

  const u16* aRow0 = s_bf + (size_t)(tbase + c) * 256;
  const u16* aRow1 = s_bf + (size_t)(tbase + 16 + c) * 256;

  bf16x8 af0[2][4];
#pragma unroll
  for (int ks = 0; ks < 4; ++ks) {
    af0[0][ks] = *(const bf16x8*)(aRow0 + ks * 32 + g * 8);
    af0[1][ks] = *(const bf16x8*)(aRow1 + ks * 32 + g * 8);
  }

  {
    const u16* bsrc = wa_t + (size_t)b0 * 64 * 256;
#pragma unroll
    for (int it = 0; it < 8; ++it) {
      int i = tid + 256 * it;
      int r = i >> 5, s = i & 31;
      ldsU[r * 32 + (s ^ (r & 7))] = *(const uint4*)(bsrc + r * 256 + s * 8);
    }
  }
  __syncthreads();

  f32x4 acc[2][4];
#pragma unroll
  for (int mf = 0; mf < 2; ++mf)
#pragma unroll
    for (int nf = 0; nf < 4; ++nf) acc[mf][nf] = (f32x4){0.f, 0.f, 0.f, 0.f};

  bf16x8 af1[2][4];
#pragma unroll
  for (int ks = 0; ks < 4; ++ks) {
    af1[0][ks] = *(const bf16x8*)(aRow0 + 128 + ks * 32 + g * 8);
    af1[1][ks] = *(const bf16x8*)(aRow1 + 128 + ks * 32 + g * 8);
  }

#pragma unroll
  for (int ks = 0; ks < 4; ++ks) {
#pragma unroll
    for (int nf = 0; nf < 4; ++nf) {
      int rr = nf * 16 + c;
      bf16x8 bfv = *(const bf16x8*)&ldsU[rr * 32 + ((ks * 4 + g) ^ (rr & 7))];
      acc[0][nf] = __builtin_amdgcn_mfma_f32_16x16x32_bf16(af0[0][ks], bfv, acc[0][nf], 0, 0, 0);
      acc[1][nf] = __builtin_amdgcn_mfma_f32_16x16x32_bf16(af0[1][ks], bfv, acc[1][nf], 0, 0, 0);
    }
  }
#pragma unroll
  for (int ks = 0; ks < 4; ++ks) {
#pragma unroll
    for (int nf = 0; nf < 4; ++nf) {
      int rr = nf * 16 + c;
      bf16x8 bfv = *(const bf16x8*)&ldsU[rr * 32 + (((ks + 4) * 4 + g) ^ (rr & 7))];
      acc[0][nf] = __builtin_amdgcn_mfma_f32_16x16x32_bf16(af1[0][ks], bfv, acc[0][nf], 0, 0, 0);
      acc[1][nf] = __builtin_amdgcn_mfma_f32_16x16x32_bf16(af1[1][ks], bfv, acc[1][nf], 0, 0, 0);
    }
  }

  const size_t pebase = (size_t)b0 * 8192;
#pragma unroll
  for (int mf = 0; mf < 2; ++mf) {
#pragma unroll
    for (int q = 0; q < 4; ++q) {
      float e0 = __expf(acc[mf][0][q]);
      float e1 = __expf(acc[mf][1][q]);
      float e2 = __expf(acc[mf][2][q]);
      float e3 = __expf(acc[mf][3][q]);
      float s = (e0 + e1) + (e2 + e3);
#pragma unroll
      for (int d = 1; d < 16; d <<= 1) s += __shfl_xor(s, d);
      int a = act[mf][q];
      int acf = a >> 4;
      float esel = (acf == 0) ? e0 : (acf == 1) ? e1 : (acf == 2) ? e2 : e3;
      if (c == (a & 15))
        peT[pebase + tbase + mf * 16 + g * 4 + q] = esel / s;
    }
  }
}

// ---------------- chunked scan: k-split, barrier-free step loop ----------------
__global__ __launch_bounds__(256) void chunk_kernel(
    const float* __restrict__ peT, const float* __restrict__ ps,
    const float* __restrict__ pb, const float* __restrict__ pc,
    float* __restrict__ Mout, float* __restrict__ lscale) {
  __shared__ float scal[64 * 196];   // per step: [b(64) | ec(64) | es(64) | pad]
  __shared__ float mxs[4];
  const int ck = blockIdx.x;
  const int tid = threadIdx.x;
  const int lane = tid & 63;
  const int w = tid >> 6;
  const int tlo = ck * 64 + 1;

#pragma unroll
  for (int it = 0; it < 16; ++it) {
    int i = tid + 256 * it;
    int st = i >> 6, j = i & 63;
    int t = tlo + st;
    if (t <= T_LEN - 1) {
      int base = t * 64 + j;
      scal[st * 196 + j]       = pb[base];
      scal[st * 196 + 64 + j]  = pc[base];
      scal[st * 196 + 128 + j] = ps[base];
    } else {
      scal[st * 196 + j]       = 0.f;
      scal[st * 196 + 64 + j]  = 1.f;
      scal[st * 196 + 128 + j] = 0.f;
    }
  }
  __syncthreads();
#pragma unroll
  for (int it = 0; it < 16; ++it) {
    int i = tid + 256 * it;
    int j = i >> 6, st = i & 63;
    int t = tlo + st;
    if (t <= T_LEN - 1) {
      float e = peT[(size_t)j * 8192 + t];
      scal[st * 196 + 64 + j]  *= e;
      scal[st * 196 + 128 + j] *= e;
    }
  }
  __syncthreads();

  const int kcol = w * 16 + (lane >> 2);
  const int roff = (lane & 3) * 16;

  float M[16];
#pragma unroll
  for (int jj = 0; jj < 16; ++jj) M[jj] = ((roff + jj) == kcol) ? 1.f : 0.f;
  float lsc = 0.f;

  for (int st8 = 0; st8 < 8; ++st8) {
#pragma unroll
    for (int s8 = 0; s8 < 8; ++s8) {
      const float* sb = &scal[(st8 * 8 + s8) * 196];
      float4 b0 = *(const float4*)(sb + roff + 0);
      float4 b1 = *(const float4*)(sb + roff + 4);
      float4 b2 = *(const float4*)(sb + roff + 8);
      float4 b3 = *(const float4*)(sb + roff + 12);
      float p0 = 0.f, p1 = 0.f, p2 = 0.f, p3 = 0.f;
      p0 = fmaf(b0.x, M[0], p0);  p1 = fmaf(b0.y, M[1], p1);
      p2 = fmaf(b0.z, M[2], p2);  p3 = fmaf(b0.w, M[3], p3);
      p0 = fmaf(b1.x, M[4], p0);  p1 = fmaf(b1.y, M[5], p1);
      p2 = fmaf(b1.z, M[6], p2);  p3 = fmaf(b1.w, M[7], p3);
      p0 = fmaf(b2.x, M[8], p0);  p1 = fmaf(b2.y, M[9], p1);
      p2 = fmaf(b2.z, M[10], p2); p3 = fmaf(b2.w, M[11], p3);
      p0 = fmaf(b3.x, M[12], p0); p1 = fmaf(b3.y, M[13], p1);
      p2 = fmaf(b3.z, M[14], p2); p3 = fmaf(b3.w, M[15], p3);
      float p = (p0 + p1) + (p2 + p3);
      p += __shfl_xor(p, 1);
      p += __shfl_xor(p, 2);
      float4 e0 = *(const float4*)(sb + 64 + roff + 0);
      float4 e1 = *(const float4*)(sb + 64 + roff + 4);
      float4 e2 = *(const float4*)(sb + 64 + roff + 8);
      float4 e3 = *(const float4*)(sb + 64 + roff + 12);
      float4 s0 = *(const float4*)(sb + 128 + roff + 0);
      float4 s1 = *(const float4*)(sb + 128 + roff + 4);
      float4 s2 = *(const float4*)(sb + 128 + roff + 8);
      float4 s3 = *(const float4*)(sb + 128 + roff + 12);
      M[0]  = fmaf(e0.x, M[0],  s0.x * p);  M[1]  = fmaf(e0.y, M[1],  s0.y * p);
      M[2]  = fmaf(e0.z, M[2],  s0.z * p);  M[3]  = fmaf(e0.w, M[3],  s0.w * p);
      M[4]  = fmaf(e1.x, M[4],  s1.x * p);  M[5]  = fmaf(e1.y, M[5],  s1.y * p);
      M[6]  = fmaf(e1.z, M[6],  s1.z * p);  M[7]  = fmaf(e1.w, M[7],  s1.w * p);
      M[8]  = fmaf(e2.x, M[8],  s2.x * p);  M[9]  = fmaf(e2.y, M[9],  s2.y * p);
      M[10] = fmaf(e2.z, M[10], s2.z * p);  M[11] = fmaf(e2.w, M[11], s2.w * p);
      M[12] = fmaf(e3.x, M[12], s3.x * p);  M[13] = fmaf(e3.y, M[13], s3.y * p);
      M[14] = fmaf(e3.z, M[14], s3.z * p);  M[15] = fmaf(e3.w, M[15], s3.w * p);
    }
    float mx = M[0];
#pragma unroll
    for (int jj = 1; jj < 16; ++jj) mx = fmaxf(mx, M[jj]);
#pragma unroll
    for (int d = 1; d < 64; d <<= 1) mx = fmaxf(mx, __shfl_xor(mx, d));
    if (lane == 0) mxs[w] = mx;
    __syncthreads();
    float bm = fmaxf(fmaxf(mxs[0], mxs[1]), fmaxf(mxs[2], mxs[3]));
    float inv = 1.f / bm;
#pragma unroll
    for (int jj = 0; jj < 16; ++jj) M[jj] *= inv;
    lsc += __logf(bm);
    __syncthreads();
  }

  float* out = Mout + (size_t)ck * 4096 + kcol * 64 + roff;
  *(float4*)(out + 0)  = make_float4(M[0],  M[1],  M[2],  M[3]);
  *(float4*)(out + 4)  = make_float4(M[4],  M[5],  M[6],  M[7]);
  *(float4*)(out + 8)  = make_float4(M[8],  M[9],  M[10], M[11]);
  *(float4*)(out + 12) = make_float4(M[12], M[13], M[14], M[15]);
  if (tid == 0) lscale[ck] = lsc;
}

// ---------------- level-1 combine: 16 groups x 8 chunk matrices ----------------
__global__ __launch_bounds__(256) void group_combine(
    const float* __restrict__ Mout, const float* __restrict__ lscale,
    float* __restrict__ Gout, float* __restrict__ glsc) {
  const int g = blockIdx.x;
  const int tid = threadIdx.x;
  const int j = tid & 63;
  const int w = tid >> 6;
  __shared__ float Xa[64 * 68];
  __shared__ float Xb[64 * 68];
  __shared__ float Ma[64 * 68];
  __shared__ float Mb[64 * 68];
  __shared__ float red[4];

  {
    const float* M0 = Mout + (size_t)(8 * g) * 4096;
    const float* M1 = Mout + (size_t)(8 * g + 1) * 4096;
    for (int idx = tid; idx < 4096; idx += 256) {
      int i = idx >> 6, r = idx & 63;
      Xa[r * 68 + i] = M0[idx];
      Ma[i * 68 + r] = M1[idx];
    }
  }
  __syncthreads();

  float lsc = 0.f;
  float* Xcur = Xa; float* Xnxt = Xb;
  float* Mcur = Ma; float* Mnxt = Mb;

  for (int m = 1; m < 8; ++m) {
    float4 pf[4];
    if (m < 7) {
      const float* Mn = Mout + (size_t)(8 * g + m + 1) * 4096;
#pragma unroll
      for (int ii = 0; ii < 4; ++ii)
        pf[ii] = *(const float4*)(Mn + tid * 4 + 1024 * ii);
    }

    float acc[16];
#pragma unroll
    for (int i = 0; i < 16; ++i) acc[i] = 0.f;

#pragma unroll 4
    for (int k = 0; k < 64; ++k) {
      float mv = Mcur[k * 68 + j];
      const float* xr = Xcur + k * 68 + (w << 4);
      float4 x0 = *(const float4*)(xr + 0);
      float4 x1 = *(const float4*)(xr + 4);
      float4 x2 = *(const float4*)(xr + 8);
      float4 x3 = *(const float4*)(xr + 12);
      acc[0]  = fmaf(mv, x0.x, acc[0]);  acc[1]  = fmaf(mv, x0.y, acc[1]);
      acc[2]  = fmaf(mv, x0.z, acc[2]);  acc[3]  = fmaf(mv, x0.w, acc[3]);
      acc[4]  = fmaf(mv, x1.x, acc[4]);  acc[5]  = fmaf(mv, x1.y, acc[5]);
      acc[6]  = fmaf(mv, x1.z, acc[6]);  acc[7]  = fmaf(mv, x1.w, acc[7]);
      acc[8]  = fmaf(mv, x2.x, acc[8]);  acc[9]  = fmaf(mv, x2.y, acc[9]);
      acc[10] = fmaf(mv, x2.z, acc[10]); acc[11] = fmaf(mv, x2.w, acc[11]);
      acc[12] = fmaf(mv, x3.x, acc[12]); acc[13] = fmaf(mv, x3.y, acc[13]);
      acc[14] = fmaf(mv, x3.z, acc[14]); acc[15] = fmaf(mv, x3.w, acc[15]);
    }

    float lm = acc[0];
#pragma unroll
    for (int i = 1; i < 16; ++i) lm = fmaxf(lm, acc[i]);
#pragma unroll
    for (int d = 1; d < 64; d <<= 1) lm = fmaxf(lm, __shfl_xor(lm, d));
    if ((tid & 63) == 0) red[w] = lm;
    __syncthreads();
    float bm = fmaxf(fmaxf(red[0], red[1]), fmaxf(red[2], red[3]));
    float inv = 1.f / bm;
    lsc += __logf(bm);
#pragma unroll
    for (int i = 0; i < 16; ++i)
      Xnxt[j * 68 + (w << 4) + i] = acc[i] * inv;
    if (m < 7) {
#pragma unroll
      for (int ii = 0; ii < 4; ++ii) {
        int idx = tid * 4 + 1024 * ii;
        int k = idx >> 6, jj = idx & 63;
        *(float4*)(Mnxt + k * 68 + jj) = pf[ii];
      }
    }
    __syncthreads();
    float* t = Xcur; Xcur = Xnxt; Xnxt = t;
    float* tm = Mcur; Mcur = Mnxt; Mnxt = tm;
  }

  float* out = Gout + (size_t)g * 4096;
  for (int idx = tid; idx < 4096; idx += 256) {
    int i = idx >> 6, r = idx & 63;
    out[idx] = Xcur[r * 68 + i];
  }
  if (tid == 0) {
    float s = lsc;
#pragma unroll
    for (int m = 0; m < 8; ++m) s += lscale[8 * g + m];
    glsc[g] = s;
  }
}

// ---------------- level-2 combine: 16 sequential mat-vecs ----------------
__global__ __launch_bounds__(256) void final_combine(
    const float* __restrict__ Gout, const float* __restrict__ glsc,
    const float* __restrict__ peT, const float* __restrict__ ps,
    const float* __restrict__ pb, float* __restrict__ out) {
  const int tid = threadIdx.x;
  const int j = tid & 63, w = tid >> 6;
  __shared__ float vsh[64];
  __shared__ float part[4 * 64];
  if (tid < 64) vsh[tid] = ps[tid] * peT[(size_t)tid * 8192];   // f0
  __syncthreads();
  double lsc = 0.0;
  for (int gph = 0; gph < 16; ++gph) {
    const float* Gc = Gout + (size_t)gph * 4096;
    const int k0 = w << 4;
    float a0 = 0.f, a1 = 0.f, a2 = 0.f, a3 = 0.f;
#pragma unroll
    for (int kk = 0; kk < 16; kk += 4) {
      a0 = fmaf(vsh[k0 + kk + 0], Gc[(k0 + kk + 0) * 64 + j], a0);
      a1 = fmaf(vsh[k0 + kk + 1], Gc[(k0 + kk + 1) * 64 + j], a1);
      a2 = fmaf(vsh[k0 + kk + 2], Gc[(k0 + kk + 2) * 64 + j], a2);
      a3 = fmaf(vsh[k0 + kk + 3], Gc[(k0 + kk + 3) * 64 + j], a3);
    }
    part[w * 64 + j] = (a0 + a1) + (a2 + a3);
    __syncthreads();
    if (w == 0) {
      float u = part[j] + part[64 + j] + part[128 + j] + part[192 + j];
      float mx = u;
#pragma unroll
      for (int d = 1; d < 64; d <<= 1) mx = fmaxf(mx, __shfl_xor(mx, d));
      vsh[j] = u / mx;
      lsc += (double)__logf(mx) + (double)glsc[gph];
    }
    __syncthreads();
  }
  if (w == 0) {
    float z = vsh[j] * pb[T_LEN * 64 + j];
#pragma unroll
    for (int d = 1; d < 64; d <<= 1) z += __shfl_xor(z, d);
    if (j == 0) out[0] = (float)(-((double)logf(z) + lsc));
  }
}

extern "C" void kernel_launch(void* const* d_in, const int* in_sizes, int n_in,
                              void* d_out, int out_size, void* d_ws, size_t ws_size,
                              hipStream_t stream) {
  const float* s_i      = (const float*)d_in[0];
  const float* W_action = (const float*)d_in[1];
  const float* W_stop   = (const float*)d_in[2];
  const float* W_start  = (const float*)d_in[3];
  const int*   actions  = (const int*)d_in[4];

  char* ws = (char*)d_ws;
  u16*   s_bf  = (u16*)(ws + WS_SBF);
  u16*   wa_t  = (u16*)(ws + WS_WAT);
  u16*   wsm_t = (u16*)(ws + WS_WSMT);
  float* peT   = (float*)(ws + WS_PE);
  float* ps    = (float*)(ws + WS_PS);
  float* pb    = (float*)(ws + WS_PB);
  float* pc    = (float*)(ws + WS_PC);
  float* Mout  = (float*)(ws + WS_MOUT);
  float* lsc   = (float*)(ws + WS_LSC);
  float* Gout  = (float*)(ws + WS_GOUT);
  float* glsc  = (float*)(ws + WS_GLSC);

  conv_all<<<2512, 256, 0, stream>>>(s_i, W_action, W_stop, W_start, s_bf, wa_t, wsm_t);
  gemm_fused<<<4225, 256, 0, stream>>>(s_bf, wa_t, wsm_t, actions, peT, ps, pb, pc);
  chunk_kernel<<<128, 256, 0, stream>>>(peT, ps, pb, pc, Mout, lsc);
  group_combine<<<16, 256, 0, stream>>>(Mout, lsc, Gout, glsc);
  final_combine<<<1, 256, 0, stream>>>(Gout, glsc, peT, ps, pb, (float*)d_out);
}